// Round 10
// baseline (2989.199 us; speedup 1.0000x reference)
//
#include <hip/hip_runtime.h>
#include <cstdint>

typedef _Float16 f16;
using f16x2 = __attribute__((ext_vector_type(2))) _Float16;
using f16x4 = __attribute__((ext_vector_type(4))) _Float16;
using f16x8 = __attribute__((ext_vector_type(8))) _Float16;
using f32x4 = __attribute__((ext_vector_type(4))) float;
using u32x4 = __attribute__((ext_vector_type(4))) uint32_t;
using i32x4 = __attribute__((ext_vector_type(4))) int;

// Newton-refined reciprocal: <=1 ulp at rcp + 2 fma (proven R9).
__device__ __forceinline__ float rcp_nr(float x) {
  float r = __builtin_amdgcn_rcpf(x);
  return fmaf(fmaf(-x, r, 1.0f), r, r);
}
__device__ __forceinline__ float sigmoidf_(float x) {
  float e = exp2f(-x * 1.44269504088896f);
  return rcp_nr(1.0f + e);
}
__device__ __forceinline__ float tanhf_(float x) {
  float e = exp2f(x * 2.88539008177793f);   // exp(2x)
  return 1.0f - 2.0f * rcp_nr(e + 1.0f);
}

// i8 MFMA, B + acc in AGPR. Accumulate form and zero-C form (fresh acc without
// 4 accvgpr_write zero-inits; zc is a loop-invariant zero f32x4 held in AGPR).
__device__ __forceinline__ void mfma_i8(i32x4& d, u32x4 a, u32x4 b) {
  asm("v_mfma_i32_16x16x64_i8 %0, %1, %2, %0"
      : "+a"(d)
      : "v"(a), "a"(b));
}
__device__ __forceinline__ void mfma_i8_z(i32x4& d, u32x4 a, u32x4 b, const i32x4& zc) {
  asm("v_mfma_i32_16x16x64_i8 %0, %1, %2, %3"
      : "=a"(d)
      : "v"(a), "a"(b), "a"(zc));
}

// ---------------- conversion / prep kernels ----------------

__global__ void f32_to_f16_kernel(const float* __restrict__ in, f16* __restrict__ out, long n4) {
  long stride = (long)gridDim.x * blockDim.x;
  for (long i = blockIdx.x * (long)blockDim.x + threadIdx.x; i < n4; i += stride) {
    f32x4 v = *(const f32x4*)(in + i * 4);
    f16x4 h;
    h[0] = (f16)v[0]; h[1] = (f16)v[1]; h[2] = (f16)v[2]; h[3] = (f16)v[3];
    *(f16x4*)(out + i * 4) = h;
  }
}

__global__ void addvec_kernel(const float* __restrict__ a, const float* __restrict__ b,
                              float* __restrict__ o, int n) {
  int i = blockIdx.x * blockDim.x + threadIdx.x;
  if (i < n) o[i] = a[i] + b[i];
}

// Per-gate-row symmetric int8 scales: qmul[r]=127/max|W_r|, dmul[r]=max|W_r|/127^2.
__global__ __launch_bounds__(256) void rowscale_kernel(const float* __restrict__ whh,
                                                       float* __restrict__ qmul,
                                                       float* __restrict__ dmul) {
  const int wv = (blockIdx.x * 256 + threadIdx.x) >> 6;  // global wave 0..63
  const int lane = threadIdx.x & 63;
  for (int rr = 0; rr < 16; ++rr) {
    int r = wv * 16 + rr;
    f32x4 v = *(const f32x4*)(whh + r * 256 + lane * 4);
    float m = fmaxf(fmaxf(fabsf(v[0]), fabsf(v[1])), fmaxf(fabsf(v[2]), fabsf(v[3])));
#pragma unroll
    for (int s = 1; s < 64; s <<= 1) m = fmaxf(m, __shfl_xor(m, s, 64));
    if (lane == 0) {
      float sr = fmaxf(m, 1e-8f);
      qmul[r] = 127.0f / sr;
      dmul[r] = sr / 16129.0f;
    }
  }
}

// int8 B-fragment prep for v_mfma_i32_16x16x64_i8 (R7-proven k-map).
__global__ void wq8_kernel(const float* __restrict__ whh, const float* __restrict__ qmul,
                           uint32_t* __restrict__ wq) {
  int i = blockIdx.x * blockDim.x + threadIdx.x;  // 65536 threads
  int d = i & 3, l = (i >> 2) & 63, c = (i >> 8) & 3, t = i >> 10;
  int r = t * 16 + (l & 15);
  int k0 = c * 64 + ((l >> 4) & 3) * 16 + d * 4;
  float qm = qmul[r];
  uint32_t out = 0;
#pragma unroll
  for (int e = 0; e < 4; ++e) {
    int q = __float2int_rn(whh[r * 256 + k0 + e] * qm);
    q = min(127, max(-127, q));
    out |= ((uint32_t)(uint8_t)(int8_t)q) << (8 * e);
  }
  wq[i] = out;
}

// ---------------- GEMM: C[m,n] = sum_k A[m,k]*B[n,k] + bias[n] ----------------

template <int OUTF32>
__global__ __launch_bounds__(256) void gemm_bt_kernel(
    const f16* __restrict__ A, const f16* __restrict__ B,
    const float* __restrict__ bias, void* __restrict__ Cout,
    int M, int N, int K) {
  __shared__ __align__(16) f16 Al[128 * 32];
  __shared__ __align__(16) f16 Bl[128 * 32];
  const int tid = threadIdx.x;
  const int lane = tid & 63, wave = tid >> 6;
  const int bn = blockIdx.x, bm = blockIdx.y;
  const int qm = (wave >> 1) * 64, qn = (wave & 1) * 64;

  f32x4 acc[4][4];
#pragma unroll
  for (int i = 0; i < 4; ++i)
#pragma unroll
    for (int j = 0; j < 4; ++j) acc[i][j] = (f32x4){0.f, 0.f, 0.f, 0.f};

  const int c0 = tid, c1 = 256 + tid;
  const int row0 = c0 >> 2, off0 = c0 & 3;
  const int row1 = c1 >> 2, off1 = c1 & 3;
  const int gmA0 = min(bm * 128 + row0, M - 1);
  const int gmA1 = min(bm * 128 + row1, M - 1);
  const int gnB0 = min(bn * 128 + row0, N - 1);
  const int gnB1 = min(bn * 128 + row1, N - 1);

  for (int k0 = 0; k0 < K; k0 += 32) {
    u32x4 ar0 = *(const u32x4*)(A + (size_t)gmA0 * K + k0 + off0 * 8);
    u32x4 ar1 = *(const u32x4*)(A + (size_t)gmA1 * K + k0 + off1 * 8);
    u32x4 br0 = *(const u32x4*)(B + (size_t)gnB0 * K + k0 + off0 * 8);
    u32x4 br1 = *(const u32x4*)(B + (size_t)gnB1 * K + k0 + off1 * 8);
    __syncthreads();  // previous iteration's LDS reads done
    *(u32x4*)&Al[c0 * 8] = ar0;
    *(u32x4*)&Al[c1 * 8] = ar1;
    *(u32x4*)&Bl[c0 * 8] = br0;
    *(u32x4*)&Bl[c1 * 8] = br1;
    __syncthreads();
    f16x8 af[4], bf[4];
#pragma unroll
    for (int mt = 0; mt < 4; ++mt)
      af[mt] = *(const f16x8*)&Al[(qm + mt * 16 + (lane & 15)) * 32 + (lane >> 4) * 8];
#pragma unroll
    for (int nt = 0; nt < 4; ++nt)
      bf[nt] = *(const f16x8*)&Bl[(qn + nt * 16 + (lane & 15)) * 32 + (lane >> 4) * 8];
#pragma unroll
    for (int mt = 0; mt < 4; ++mt)
#pragma unroll
      for (int nt = 0; nt < 4; ++nt)
        acc[mt][nt] = __builtin_amdgcn_mfma_f32_16x16x32_f16(af[mt], bf[nt], acc[mt][nt], 0, 0, 0);
  }

#pragma unroll
  for (int mt = 0; mt < 4; ++mt)
#pragma unroll
    for (int nt = 0; nt < 4; ++nt)
#pragma unroll
      for (int j = 0; j < 4; ++j) {
        int gm = bm * 128 + qm + mt * 16 + (lane >> 4) * 4 + j;
        int gn = bn * 128 + qn + nt * 16 + (lane & 15);
        if (gm < M && gn < N) {
          float v = acc[mt][nt][j] + bias[gn];
          if (OUTF32)
            ((float*)Cout)[(size_t)gm * N + gn] = v;
          else
            ((f16*)Cout)[(size_t)gm * N + gn] = (f16)v;
        }
      }
}

// ---------------- persistent LSTM recurrence: two-batch phase pipeline ----------------
// 32 blocks x 512 threads (8 waves), each block runs batches bA=2*blk, bB=2*blk+1,
// SHARING one weight copy in AGPRs (R9-proven layout: wave w holds tiles w+8j, j<8;
// 128 a-regs) with per-batch acc sets (2 x 32 a = 64) + zc (4) = 196 AGPR.
// Per iteration t:
//   a: act_A(t)  (acc_A = W.h_A(t) from prev phase e)  -> h_A(t+1) LDS+global
//   b: MFMA_B(t) (reads h_B(t))          [independent of a -> VALU || MFMA overlap]
//   c: lgkmcnt(0); barrier               (h_A(t+1) visible)
//   d: act_B(t)  -> h_B(t+1)
//   e: MFMA_A(t+1) (reads h_A(t+1))      [independent of d]
//   f: lgkmcnt(0); barrier               (h_B(t+1) visible)
// Two-level h per batch (R7-proven): A row0 = h_hi, row1 = h_lo; gate =
// D0*dmul + D1*dmul/127 + xg (fma-reassociated). Prologue: acc_A = W.0 = 0.

__device__ __forceinline__ void mfma_phase(i32x4* acc, const uint8_t* hq,
                                           const u32x4 (*wt)[4], int kg,
                                           const i32x4& zc) {
  {
    u32x4 afr = *(const u32x4*)(hq + 0 * 64 + kg * 16);
#pragma unroll
    for (int j = 0; j < 8; ++j) mfma_i8_z(acc[j], afr, wt[j][0], zc);
  }
#pragma unroll
  for (int c = 1; c < 4; ++c) {
    u32x4 afr = *(const u32x4*)(hq + c * 64 + kg * 16);
#pragma unroll
    for (int j = 0; j < 8; ++j) mfma_i8(acc[j], afr, wt[j][c]);
  }
}

__device__ __forceinline__ void act_step(
    const i32x4* acc, const float* sc, const float* sc2, const f16* xc,
    float& cA, float& cB, uint8_t* hn, f16* hob_row, int uA, int uB, int lane) {
  float xv[8];
#pragma unroll
  for (int j = 0; j < 8; ++j) xv[j] = (float)xc[j];
  float gI_A = fmaf((float)acc[0][0], sc[0], fmaf((float)acc[0][1], sc2[0], xv[0]));
  float gI_B = fmaf((float)acc[1][0], sc[1], fmaf((float)acc[1][1], sc2[1], xv[1]));
  float gF_A = fmaf((float)acc[2][0], sc[2], fmaf((float)acc[2][1], sc2[2], xv[2]));
  float gF_B = fmaf((float)acc[3][0], sc[3], fmaf((float)acc[3][1], sc2[3], xv[3]));
  float gG_A = fmaf((float)acc[4][0], sc[4], fmaf((float)acc[4][1], sc2[4], xv[4]));
  float gG_B = fmaf((float)acc[5][0], sc[5], fmaf((float)acc[5][1], sc2[5], xv[5]));
  float gO_A = fmaf((float)acc[6][0], sc[6], fmaf((float)acc[6][1], sc2[6], xv[6]));
  float gO_B = fmaf((float)acc[7][0], sc[7], fmaf((float)acc[7][1], sc2[7], xv[7]));
  float iA = sigmoidf_(gI_A), iB = sigmoidf_(gI_B);
  float fA = sigmoidf_(gF_A), fB = sigmoidf_(gF_B);
  float gA = tanhf_(gG_A),   gB = tanhf_(gG_B);
  float oA = sigmoidf_(gO_A), oB = sigmoidf_(gO_B);
  cA = fA * cA + iA * gA;
  cB = fB * cB + iB * gB;
  float hA = oA * tanhf_(cA);
  float hB = oB * tanhf_(cB);
  int hiA = __float2int_rn(hA * 127.0f);
  int hiB = __float2int_rn(hB * 127.0f);
  int loA = __float2int_rn(fmaf((float)hiA, -127.0f, hA * 16129.0f));
  int loB = __float2int_rn(fmaf((float)hiB, -127.0f, hB * 16129.0f));
  if (lane < 16) {
    hn[uA] = (uint8_t)(int8_t)hiA;
    hn[uB] = (uint8_t)(int8_t)hiB;
    hn[256 + uA] = (uint8_t)(int8_t)loA;
    hn[256 + uB] = (uint8_t)(int8_t)loB;
    hob_row[uA] = (f16)hA;   // global h (vmcnt floats, never drained)
    hob_row[uB] = (f16)hB;
  }
}

__global__ __launch_bounds__(512, 2) void lstm_rec2_kernel(
    const f16* __restrict__ xg,          // [B*T, 1024], biases included
    const u32x4* __restrict__ wq,        // [64 t][4 c][64 l] u32x4 int8 frags
    const float* __restrict__ dmul,      // [1024] per-row dequant scale
    f16* __restrict__ h_out,             // [B*T, 256]
    int T) {
  __shared__ __align__(16) uint8_t h8[2][2][512];  // [batch][buf][hi 256|lo 256]
  const int bA = blockIdx.x * 2, bB = bA + 1;
  const int tid = threadIdx.x;
  const int w = tid >> 6, lane = tid & 63;
  const int l15 = lane & 15, kg = (lane >> 4) & 3;
  const int base = w * 16 + l15;
  const int uA = base, uB = base + 128;
  const int asel = (l15 == 1) ? 256 : 0;  // row1 lanes read the lo slice

  u32x4 wt[8][4];
#pragma unroll
  for (int j = 0; j < 8; ++j)
#pragma unroll
    for (int c = 0; c < 4; ++c)
      wt[j][c] = wq[((w + 8 * j) * 4 + c) * 64 + lane];
  float sc[8], sc2[8];
#pragma unroll
  for (int j = 0; j < 8; ++j) {
    sc[j] = dmul[base + 128 * j];
    sc2[j] = sc[j] * (1.0f / 127.0f);
  }

  ((uint32_t*)h8)[tid] = 0;   // zero all 4 buffers (2 KB, 512 threads)
  float cA0 = 0.f, cA1 = 0.f, cB0 = 0.f, cB1 = 0.f;
  __syncthreads();

  const f16* xtA = xg + (size_t)bA * T * 1024;
  const f16* xtB = xg + (size_t)bB * T * 1024;
  f16* hobA = h_out + (size_t)bA * T * 256;
  f16* hobB = h_out + (size_t)bB * T * 256;

  const i32x4 zc = (i32x4){0, 0, 0, 0};
  i32x4 accA[8], accB[8];
#pragma unroll
  for (int j = 0; j < 8; ++j) accA[j] = zc;   // = W . h_A(0) = 0

  f16 xcA[8], xcB[8];
#pragma unroll
  for (int j = 0; j < 8; ++j) {
    xcA[j] = xtA[base + 128 * j];
    xcB[j] = xtB[base + 128 * j];
  }

  for (int t = 0; t < T; ++t) {
    // a: act_A(t) -> h_A(t+1);  b: MFMA_B(t) (independent -> overlaps a's VALU)
    act_step(accA, sc, sc2, xcA, cA0, cA1,
             (uint8_t*)h8[0][(t + 1) & 1], hobA + (size_t)t * 256, uA, uB, lane);
    {
      const f16* xnA = (t + 1 < T) ? xtA + 1024 : xtA;
#pragma unroll
      for (int j = 0; j < 8; ++j) xcA[j] = xnA[base + 128 * j];
      xtA = xnA;
    }
    mfma_phase(accB, h8[1][t & 1] + asel, wt, kg, zc);
    // c: h_A(t+1) + B-frag reads complete
    asm volatile("s_waitcnt lgkmcnt(0)" ::: "memory");
    __builtin_amdgcn_s_barrier();
    __builtin_amdgcn_sched_barrier(0);
    // d: act_B(t) -> h_B(t+1);  e: MFMA_A(t+1) (independent -> overlaps d's VALU)
    act_step(accB, sc, sc2, xcB, cB0, cB1,
             (uint8_t*)h8[1][(t + 1) & 1], hobB + (size_t)t * 256, uA, uB, lane);
    {
      const f16* xnB = (t + 1 < T) ? xtB + 1024 : xtB;
#pragma unroll
      for (int j = 0; j < 8; ++j) xcB[j] = xnB[base + 128 * j];
      xtB = xnB;
    }
    mfma_phase(accA, h8[0][(t + 1) & 1] + asel, wt, kg, zc);
    // f: h_B(t+1) + A-frag reads complete
    asm volatile("s_waitcnt lgkmcnt(0)" ::: "memory");
    __builtin_amdgcn_s_barrier();
    __builtin_amdgcn_sched_barrier(0);
  }
}

// ---------------- fused LayerNorm + attention pooling ----------------
// one block per batch, 256 threads.

__global__ __launch_bounds__(256) void ln_attn_kernel(
    const f16* __restrict__ h2, const float* __restrict__ lnw,
    const float* __restrict__ lnb, const float* __restrict__ aw,
    f16* __restrict__ att_out) {
  const int b = blockIdx.x, tid = threadIdx.x;
  const int lane = tid & 63, wave = tid >> 6;
  __shared__ float smu[512], sis[512], ssc[512];
  __shared__ float vbuf[256];
  __shared__ float red[16];

  float vj = aw[tid] * lnw[tid];
  float uj = aw[tid] * lnb[tid];
  vbuf[tid] = vj;
  float rv = vj, ru = uj;
#pragma unroll
  for (int m = 1; m < 64; m <<= 1) { rv += __shfl_xor(rv, m, 64); ru += __shfl_xor(ru, m, 64); }
  if (lane == 0) { red[wave] = rv; red[4 + wave] = ru; }
  __syncthreads();
  const float Vsum = red[0] + red[1] + red[2] + red[3];
  const float Csum = red[4] + red[5] + red[6] + red[7];
  const f32x4 v4 = *(const f32x4*)&vbuf[lane * 4];
  const f16* hb = h2 + (size_t)b * 512 * 256;

  for (int tt = wave; tt < 512; tt += 4) {
    f16x4 hv = *(const f16x4*)(hb + (size_t)tt * 256 + lane * 4);
    float h0 = (float)hv[0], h1 = (float)hv[1], h2v = (float)hv[2], h3 = (float)hv[3];
    float s1 = h0 + h1 + h2v + h3;
    float s2 = h0 * h0 + h1 * h1 + h2v * h2v + h3 * h3;
    float sv = h0 * v4[0] + h1 * v4[1] + h2v * v4[2] + h3 * v4[3];
#pragma unroll
    for (int m = 1; m < 64; m <<= 1) {
      s1 += __shfl_xor(s1, m, 64);
      s2 += __shfl_xor(s2, m, 64);
      sv += __shfl_xor(sv, m, 64);
    }
    if (lane == 0) {
      float mu = s1 * (1.0f / 256.0f);
      float var = s2 * (1.0f / 256.0f) - mu * mu;
      float is = rsqrtf(var + 1e-5f);
      smu[tt] = mu; sis[tt] = is;
      ssc[tt] = (sv - mu * Vsum) * is + Csum;
    }
  }
  __syncthreads();
  // softmax over 512 scores
  float a0 = ssc[tid], a1 = ssc[tid + 256];
  float mx = fmaxf(a0, a1);
#pragma unroll
  for (int m = 1; m < 64; m <<= 1) mx = fmaxf(mx, __shfl_xor(mx, m, 64));
  if (lane == 0) red[wave] = mx;
  __syncthreads();
  mx = fmaxf(fmaxf(red[0], red[1]), fmaxf(red[2], red[3]));
  __syncthreads();  // protect red reuse
  float p0 = exp2f((a0 - mx) * 1.44269504f);
  float p1 = exp2f((a1 - mx) * 1.44269504f);
  float ps = p0 + p1;
  float pm = p0 * smu[tid] * sis[tid] + p1 * smu[tid + 256] * sis[tid + 256];
#pragma unroll
  for (int m = 1; m < 64; m <<= 1) { ps += __shfl_xor(ps, m, 64); pm += __shfl_xor(pm, m, 64); }
  if (lane == 0) { red[wave] = ps; red[8 + wave] = pm; }
  __syncthreads();
  const float S = red[0] + red[1] + red[2] + red[3];
  const float PM = (red[8] + red[9] + red[10] + red[11]) / S;
  ssc[tid] = p0 / S * sis[tid];          // alpha_t
  ssc[tid + 256] = p1 / S * sis[tid + 256];
  __syncthreads();
  // pass 2: attended_j = lnw_j*(sum_t alpha_t h_tj - PM) + lnb_j
  float acc = 0.f;
  for (int t = 0; t < 512; ++t) acc += ssc[t] * (float)hb[(size_t)t * 256 + tid];
  float att = lnw[tid] * (acc - PM) + lnb[tid];
  att_out[b * 256 + tid] = (f16)att;
}

// ---------------- launch ----------------

extern "C" void kernel_launch(void* const* d_in, const int* in_sizes, int n_in,
                              void* d_out, int out_size, void* d_ws, size_t ws_size,
                              hipStream_t stream) {
  (void)in_sizes; (void)n_in; (void)out_size; (void)ws_size;
  const float* x    = (const float*)d_in[0];
  const float* wih0 = (const float*)d_in[1];
  const float* whh0 = (const float*)d_in[2];
  const float* bih0 = (const float*)d_in[3];
  const float* bhh0 = (const float*)d_in[4];
  const float* wih1 = (const float*)d_in[5];
  const float* whh1 = (const float*)d_in[6];
  const float* bih1 = (const float*)d_in[7];
  const float* bhh1 = (const float*)d_in[8];
  const float* lnw  = (const float*)d_in[9];
  const float* lnb  = (const float*)d_in[10];
  const float* aw   = (const float*)d_in[11];
  const float* fcw  = (const float*)d_in[12];
  const float* fcb  = (const float*)d_in[13];

  char* ws = (char*)d_ws;
  f16* x_h      = (f16*)(ws + 0);            // 50331648 B; region reused after GEMM0:
  f16* h1       = (f16*)(ws + 0);            //   h1: 16777216 B
  f16* h2       = (f16*)(ws + 16777216);     //   h2: 16777216 B
  f16* wih0_h   = (f16*)(ws + 50331648);     // 1572864
  f16* wih1_h   = (f16*)(ws + 51904512);     // 524288
  f16* fcw_h    = (f16*)(ws + 52428800);     // 15627264
  uint32_t* wq0 = (uint32_t*)(ws + 68056064);// 262144
  uint32_t* wq1 = (uint32_t*)(ws + 68318208);// 262144
  float* qmul0  = (float*)(ws + 68580352);   // 4096
  float* dmul0  = (float*)(ws + 68584448);   // 4096
  float* qmul1  = (float*)(ws + 68588544);   // 4096
  float* dmul1  = (float*)(ws + 68592640);   // 4096
  float* bsum0  = (float*)(ws + 69104640);   // 4096
  float* bsum1  = (float*)(ws + 69108736);   // 4096
  f16* att_h    = (f16*)(ws + 69112832);     // 32768
  f16* xg       = (f16*)(ws + 69145600);     // 67108864 (shared by both layers)

  f32_to_f16_kernel<<<4096, 256, 0, stream>>>(x, x_h, 25165824 / 4);
  f32_to_f16_kernel<<<768, 256, 0, stream>>>(wih0, wih0_h, 786432 / 4);
  f32_to_f16_kernel<<<256, 256, 0, stream>>>(wih1, wih1_h, 262144 / 4);
  f32_to_f16_kernel<<<2048, 256, 0, stream>>>(fcw, fcw_h, 7813632 / 4);
  addvec_kernel<<<4, 256, 0, stream>>>(bih0, bhh0, bsum0, 1024);
  addvec_kernel<<<4, 256, 0, stream>>>(bih1, bhh1, bsum1, 1024);
  rowscale_kernel<<<16, 256, 0, stream>>>(whh0, qmul0, dmul0);
  rowscale_kernel<<<16, 256, 0, stream>>>(whh1, qmul1, dmul1);
  wq8_kernel<<<256, 256, 0, stream>>>(whh0, qmul0, wq0);
  wq8_kernel<<<256, 256, 0, stream>>>(whh1, qmul1, wq1);

  // layer 0: xg0 = x @ w_ih0^T + (b_ih0 + b_hh0)
  gemm_bt_kernel<0><<<dim3(8, 256), 256, 0, stream>>>(x_h, wih0_h, bsum0, xg, 32768, 1024, 768);
  lstm_rec2_kernel<<<32, 512, 0, stream>>>(xg, (const u32x4*)wq0, dmul0, h1, 512);
  // layer 1
  gemm_bt_kernel<0><<<dim3(8, 256), 256, 0, stream>>>(h1, wih1_h, bsum1, xg, 32768, 1024, 256);
  lstm_rec2_kernel<<<32, 512, 0, stream>>>(xg, (const u32x4*)wq1, dmul1, h2, 512);
  // LN + attention pooling
  ln_attn_kernel<<<64, 256, 0, stream>>>(h2, lnw, lnb, aw, att_h);
  // FC: out = attended @ fc_w^T + fc_b  (fp32 out)
  gemm_bt_kernel<1><<<dim3(239, 1), 256, 0, stream>>>(att_h, fcw_h, fcb, d_out, 64, 30522, 256);
}

// Round 11
// 1766.110 us; speedup vs baseline: 1.6925x; 1.6925x over previous
//
#include <hip/hip_runtime.h>
#include <cstdint>

typedef _Float16 f16;
using f16x2 = __attribute__((ext_vector_type(2))) _Float16;
using f16x4 = __attribute__((ext_vector_type(4))) _Float16;
using f16x8 = __attribute__((ext_vector_type(8))) _Float16;
using f32x4 = __attribute__((ext_vector_type(4))) float;
using u32x4 = __attribute__((ext_vector_type(4))) uint32_t;
using i32x4 = __attribute__((ext_vector_type(4))) int;

// Newton-refined reciprocal: <=1 ulp at rcp + 2 fma (proven R9).
__device__ __forceinline__ float rcp_nr(float x) {
  float r = __builtin_amdgcn_rcpf(x);
  return fmaf(fmaf(-x, r, 1.0f), r, r);
}
__device__ __forceinline__ float sigmoidf_(float x) {
  float e = exp2f(-x * 1.44269504088896f);
  return rcp_nr(1.0f + e);
}
__device__ __forceinline__ float tanhf_(float x) {
  float e = exp2f(x * 2.88539008177793f);   // exp(2x)
  return 1.0f - 2.0f * rcp_nr(e + 1.0f);
}

// i8 MFMA, B + acc in AGPR. Accumulate form and zero-C form (fresh acc without
// accvgpr_write zero-inits; zc is a loop-invariant zero held in AGPR).
__device__ __forceinline__ void mfma_i8(i32x4& d, u32x4 a, u32x4 b) {
  asm("v_mfma_i32_16x16x64_i8 %0, %1, %2, %0"
      : "+a"(d)
      : "v"(a), "a"(b));
}
__device__ __forceinline__ void mfma_i8_z(i32x4& d, u32x4 a, u32x4 b, const i32x4& zc) {
  asm("v_mfma_i32_16x16x64_i8 %0, %1, %2, %3"
      : "=a"(d)
      : "v"(a), "a"(b), "a"(zc));
}

// ---------------- conversion / prep kernels ----------------

__global__ void f32_to_f16_kernel(const float* __restrict__ in, f16* __restrict__ out, long n4) {
  long stride = (long)gridDim.x * blockDim.x;
  for (long i = blockIdx.x * (long)blockDim.x + threadIdx.x; i < n4; i += stride) {
    f32x4 v = *(const f32x4*)(in + i * 4);
    f16x4 h;
    h[0] = (f16)v[0]; h[1] = (f16)v[1]; h[2] = (f16)v[2]; h[3] = (f16)v[3];
    *(f16x4*)(out + i * 4) = h;
  }
}

__global__ void addvec_kernel(const float* __restrict__ a, const float* __restrict__ b,
                              float* __restrict__ o, int n) {
  int i = blockIdx.x * blockDim.x + threadIdx.x;
  if (i < n) o[i] = a[i] + b[i];
}

// Per-gate-row symmetric int8 scales: qmul[r]=127/max|W_r|, dmul[r]=max|W_r|/127^2.
__global__ __launch_bounds__(256) void rowscale_kernel(const float* __restrict__ whh,
                                                       float* __restrict__ qmul,
                                                       float* __restrict__ dmul) {
  const int wv = (blockIdx.x * 256 + threadIdx.x) >> 6;  // global wave 0..63
  const int lane = threadIdx.x & 63;
  for (int rr = 0; rr < 16; ++rr) {
    int r = wv * 16 + rr;
    f32x4 v = *(const f32x4*)(whh + r * 256 + lane * 4);
    float m = fmaxf(fmaxf(fabsf(v[0]), fabsf(v[1])), fmaxf(fabsf(v[2]), fabsf(v[3])));
#pragma unroll
    for (int s = 1; s < 64; s <<= 1) m = fmaxf(m, __shfl_xor(m, s, 64));
    if (lane == 0) {
      float sr = fmaxf(m, 1e-8f);
      qmul[r] = 127.0f / sr;
      dmul[r] = sr / 16129.0f;
    }
  }
}

// int8 B-fragment prep for v_mfma_i32_16x16x64_i8 (R7-proven k-map).
__global__ void wq8_kernel(const float* __restrict__ whh, const float* __restrict__ qmul,
                           uint32_t* __restrict__ wq) {
  int i = blockIdx.x * blockDim.x + threadIdx.x;  // 65536 threads
  int d = i & 3, l = (i >> 2) & 63, c = (i >> 8) & 3, t = i >> 10;
  int r = t * 16 + (l & 15);
  int k0 = c * 64 + ((l >> 4) & 3) * 16 + d * 4;
  float qm = qmul[r];
  uint32_t out = 0;
#pragma unroll
  for (int e = 0; e < 4; ++e) {
    int q = __float2int_rn(whh[r * 256 + k0 + e] * qm);
    q = min(127, max(-127, q));
    out |= ((uint32_t)(uint8_t)(int8_t)q) << (8 * e);
  }
  wq[i] = out;
}

// ---------------- GEMM: C[m,n] = sum_k A[m,k]*B[n,k] + bias[n] ----------------

template <int OUTF32>
__global__ __launch_bounds__(256) void gemm_bt_kernel(
    const f16* __restrict__ A, const f16* __restrict__ B,
    const float* __restrict__ bias, void* __restrict__ Cout,
    int M, int N, int K) {
  __shared__ __align__(16) f16 Al[128 * 32];
  __shared__ __align__(16) f16 Bl[128 * 32];
  const int tid = threadIdx.x;
  const int lane = tid & 63, wave = tid >> 6;
  const int bn = blockIdx.x, bm = blockIdx.y;
  const int qm = (wave >> 1) * 64, qn = (wave & 1) * 64;

  f32x4 acc[4][4];
#pragma unroll
  for (int i = 0; i < 4; ++i)
#pragma unroll
    for (int j = 0; j < 4; ++j) acc[i][j] = (f32x4){0.f, 0.f, 0.f, 0.f};

  const int c0 = tid, c1 = 256 + tid;
  const int row0 = c0 >> 2, off0 = c0 & 3;
  const int row1 = c1 >> 2, off1 = c1 & 3;
  const int gmA0 = min(bm * 128 + row0, M - 1);
  const int gmA1 = min(bm * 128 + row1, M - 1);
  const int gnB0 = min(bn * 128 + row0, N - 1);
  const int gnB1 = min(bn * 128 + row1, N - 1);

  for (int k0 = 0; k0 < K; k0 += 32) {
    u32x4 ar0 = *(const u32x4*)(A + (size_t)gmA0 * K + k0 + off0 * 8);
    u32x4 ar1 = *(const u32x4*)(A + (size_t)gmA1 * K + k0 + off1 * 8);
    u32x4 br0 = *(const u32x4*)(B + (size_t)gnB0 * K + k0 + off0 * 8);
    u32x4 br1 = *(const u32x4*)(B + (size_t)gnB1 * K + k0 + off1 * 8);
    __syncthreads();  // previous iteration's LDS reads done
    *(u32x4*)&Al[c0 * 8] = ar0;
    *(u32x4*)&Al[c1 * 8] = ar1;
    *(u32x4*)&Bl[c0 * 8] = br0;
    *(u32x4*)&Bl[c1 * 8] = br1;
    __syncthreads();
    f16x8 af[4], bf[4];
#pragma unroll
    for (int mt = 0; mt < 4; ++mt)
      af[mt] = *(const f16x8*)&Al[(qm + mt * 16 + (lane & 15)) * 32 + (lane >> 4) * 8];
#pragma unroll
    for (int nt = 0; nt < 4; ++nt)
      bf[nt] = *(const f16x8*)&Bl[(qn + nt * 16 + (lane & 15)) * 32 + (lane >> 4) * 8];
#pragma unroll
    for (int mt = 0; mt < 4; ++mt)
#pragma unroll
      for (int nt = 0; nt < 4; ++nt)
        acc[mt][nt] = __builtin_amdgcn_mfma_f32_16x16x32_f16(af[mt], bf[nt], acc[mt][nt], 0, 0, 0);
  }

#pragma unroll
  for (int mt = 0; mt < 4; ++mt)
#pragma unroll
    for (int nt = 0; nt < 4; ++nt)
#pragma unroll
      for (int j = 0; j < 4; ++j) {
        int gm = bm * 128 + qm + mt * 16 + (lane >> 4) * 4 + j;
        int gn = bn * 128 + qn + nt * 16 + (lane & 15);
        if (gm < M && gn < N) {
          float v = acc[mt][nt][j] + bias[gn];
          if (OUTF32)
            ((float*)Cout)[(size_t)gm * N + gn] = v;
          else
            ((f16*)Cout)[(size_t)gm * N + gn] = (f16)v;
        }
      }
}

// ---------------- persistent LSTM recurrence (int8 MFMA, two-level h) ----------------
// R9-PROVEN GEOMETRY (729 us/layer, absmax 0.0098): 64 blocks x 512 threads (8 waves),
// 8 weight tiles/wave in AGPR (128 + 32 acc + 4 zc = 164 a-regs), two-level h
// (A row0 = h_hi, row1 = h_lo), 1 barrier/step, xg prefetch, NR-rcp activations.
// R11 delta (pure instruction REORDERING, zero numerics change):
//   - MFMA phase split by unit group: uA tiles (a0,a2,a4,a6) issue first, uB tiles
//     (a1,a3,a5,a7) second; act_uA depends only on the uA accs, so the scheduler can
//     overlap act_uA's VALU with the uB MFMAs still executing (R9 serialized
//     [all MFMA] -> [all act], idling each pipe in turn).
//   - zero-C first chunk (mfma_i8_z) kills 32 accvgpr_write zero-inits per step
//     (proven in R10, which passed correctness).

__global__ __launch_bounds__(512, 2) void lstm_rec_kernel(
    const f16* __restrict__ xg,          // [B*T, 1024], biases included
    const u32x4* __restrict__ wq,        // [64 t][4 c][64 l] u32x4 int8 frags
    const float* __restrict__ dmul,      // [1024] per-row dequant scale
    f16* __restrict__ h_out,             // [B*T, 256]
    int T) {
  __shared__ __align__(16) uint8_t h8[2][512];   // [hi 256 | lo 256], double-buffered
  const int b = blockIdx.x;
  const int tid = threadIdx.x;
  const int w = tid >> 6, lane = tid & 63;
  const int l15 = lane & 15, kg = (lane >> 4) & 3;
  const int base = w * 16 + l15;        // row(j) = base + 128*j ; uA=base, uB=base+128
  const int uA = base, uB = base + 128;
  const int asel = (l15 == 1) ? 256 : 0;  // row1 lanes read the lo slice

  // all 8 tiles -> AGPR (used only via "a" asm operands)
  u32x4 wt[8][4];
#pragma unroll
  for (int j = 0; j < 8; ++j)
#pragma unroll
    for (int c = 0; c < 4; ++c)
      wt[j][c] = wq[((w + 8 * j) * 4 + c) * 64 + lane];
  float sc[8], sc2[8];
#pragma unroll
  for (int j = 0; j < 8; ++j) {
    sc[j] = dmul[base + 128 * j];
    sc2[j] = sc[j] * (1.0f / 127.0f);
  }

  if (tid < 256) ((uint32_t*)h8)[tid] = 0;   // zero both buffers (1 KB)
  float cA = 0.f, cB = 0.f;
  __syncthreads();

  const f16* xt = xg + (size_t)b * T * 1024;
  f16* hob = h_out + (size_t)b * T * 256;

  // prologue: prefetch step-0 xg contributions
  f16 xc[8];
#pragma unroll
  for (int j = 0; j < 8; ++j) xc[j] = xt[base + 128 * j];

  const i32x4 zc = (i32x4){0, 0, 0, 0};

  for (int t = 0; t < T; ++t) {
    // consume prefetched xg; issue next step's loads (hidden under this step)
    float xv[8];
#pragma unroll
    for (int j = 0; j < 8; ++j) xv[j] = (float)xc[j];
    const f16* xn = (t + 1 < T) ? xt + 1024 : xt;
#pragma unroll
    for (int j = 0; j < 8; ++j) xc[j] = xn[base + 128 * j];

    const uint8_t* hq = h8[t & 1] + asel;
    u32x4 af0 = *(const u32x4*)(hq + 0 * 64 + kg * 16);
    u32x4 af1 = *(const u32x4*)(hq + 1 * 64 + kg * 16);
    u32x4 af2 = *(const u32x4*)(hq + 2 * 64 + kg * 16);
    u32x4 af3 = *(const u32x4*)(hq + 3 * 64 + kg * 16);

    i32x4 a0, a1, a2, a3, a4, a5, a6, a7;
    // phase 1: uA gate tiles (i,f,g,o of uA)
    mfma_i8_z(a0, af0, wt[0][0], zc);
    mfma_i8_z(a2, af0, wt[2][0], zc);
    mfma_i8_z(a4, af0, wt[4][0], zc);
    mfma_i8_z(a6, af0, wt[6][0], zc);
    mfma_i8(a0, af1, wt[0][1]); mfma_i8(a2, af1, wt[2][1]);
    mfma_i8(a4, af1, wt[4][1]); mfma_i8(a6, af1, wt[6][1]);
    mfma_i8(a0, af2, wt[0][2]); mfma_i8(a2, af2, wt[2][2]);
    mfma_i8(a4, af2, wt[4][2]); mfma_i8(a6, af2, wt[6][2]);
    mfma_i8(a0, af3, wt[0][3]); mfma_i8(a2, af3, wt[2][3]);
    mfma_i8(a4, af3, wt[4][3]); mfma_i8(a6, af3, wt[6][3]);
    // phase 2: uB gate tiles (independent of act_uA below -> pipes overlap)
    mfma_i8_z(a1, af0, wt[1][0], zc);
    mfma_i8_z(a3, af0, wt[3][0], zc);
    mfma_i8_z(a5, af0, wt[5][0], zc);
    mfma_i8_z(a7, af0, wt[7][0], zc);
    mfma_i8(a1, af1, wt[1][1]); mfma_i8(a3, af1, wt[3][1]);
    mfma_i8(a5, af1, wt[5][1]); mfma_i8(a7, af1, wt[7][1]);
    mfma_i8(a1, af2, wt[1][2]); mfma_i8(a3, af2, wt[3][2]);
    mfma_i8(a5, af2, wt[5][2]); mfma_i8(a7, af2, wt[7][2]);
    mfma_i8(a1, af3, wt[1][3]); mfma_i8(a3, af3, wt[3][3]);
    mfma_i8(a5, af3, wt[5][3]); mfma_i8(a7, af3, wt[7][3]);

    uint8_t* hn = (uint8_t*)h8[(t + 1) & 1];
    // act uA (reads only a0,a2,a4,a6 -> can start while uB MFMAs execute)
    {
      float gI = (float)a0[0] * sc[0] + (float)a0[1] * sc2[0] + xv[0];
      float gF = (float)a2[0] * sc[2] + (float)a2[1] * sc2[2] + xv[2];
      float gG = (float)a4[0] * sc[4] + (float)a4[1] * sc2[4] + xv[4];
      float gO = (float)a6[0] * sc[6] + (float)a6[1] * sc2[6] + xv[6];
      float iv = sigmoidf_(gI), fv = sigmoidf_(gF);
      float gv = tanhf_(gG),   ov = sigmoidf_(gO);
      cA = fv * cA + iv * gv;
      float hA = ov * tanhf_(cA);
      int hi = __float2int_rn(hA * 127.0f);
      int lo = __float2int_rn(fmaf((float)hi, -127.0f, hA * 16129.0f));
      if (lane < 16) {
        hn[uA] = (uint8_t)(int8_t)hi;
        hn[256 + uA] = (uint8_t)(int8_t)lo;
        hob[(size_t)t * 256 + uA] = (f16)hA;
      }
    }
    // act uB
    {
      float gI = (float)a1[0] * sc[1] + (float)a1[1] * sc2[1] + xv[1];
      float gF = (float)a3[0] * sc[3] + (float)a3[1] * sc2[3] + xv[3];
      float gG = (float)a5[0] * sc[5] + (float)a5[1] * sc2[5] + xv[5];
      float gO = (float)a7[0] * sc[7] + (float)a7[1] * sc2[7] + xv[7];
      float iv = sigmoidf_(gI), fv = sigmoidf_(gF);
      float gv = tanhf_(gG),   ov = sigmoidf_(gO);
      cB = fv * cB + iv * gv;
      float hB = ov * tanhf_(cB);
      int hi = __float2int_rn(hB * 127.0f);
      int lo = __float2int_rn(fmaf((float)hi, -127.0f, hB * 16129.0f));
      if (lane < 16) {
        hn[uB] = (uint8_t)(int8_t)hi;
        hn[256 + uB] = (uint8_t)(int8_t)lo;
        hob[(size_t)t * 256 + uB] = (f16)hB;
      }
    }
    xt += 1024;
    asm volatile("s_waitcnt lgkmcnt(0)" ::: "memory");  // h8 writes visible
    __builtin_amdgcn_s_barrier();
    __builtin_amdgcn_sched_barrier(0);
  }
}

// ---------------- fused LayerNorm + attention pooling ----------------
// one block per batch, 256 threads.

__global__ __launch_bounds__(256) void ln_attn_kernel(
    const f16* __restrict__ h2, const float* __restrict__ lnw,
    const float* __restrict__ lnb, const float* __restrict__ aw,
    f16* __restrict__ att_out) {
  const int b = blockIdx.x, tid = threadIdx.x;
  const int lane = tid & 63, wave = tid >> 6;
  __shared__ float smu[512], sis[512], ssc[512];
  __shared__ float vbuf[256];
  __shared__ float red[16];

  float vj = aw[tid] * lnw[tid];
  float uj = aw[tid] * lnb[tid];
  vbuf[tid] = vj;
  float rv = vj, ru = uj;
#pragma unroll
  for (int m = 1; m < 64; m <<= 1) { rv += __shfl_xor(rv, m, 64); ru += __shfl_xor(ru, m, 64); }
  if (lane == 0) { red[wave] = rv; red[4 + wave] = ru; }
  __syncthreads();
  const float Vsum = red[0] + red[1] + red[2] + red[3];
  const float Csum = red[4] + red[5] + red[6] + red[7];
  const f32x4 v4 = *(const f32x4*)&vbuf[lane * 4];
  const f16* hb = h2 + (size_t)b * 512 * 256;

  for (int tt = wave; tt < 512; tt += 4) {
    f16x4 hv = *(const f16x4*)(hb + (size_t)tt * 256 + lane * 4);
    float h0 = (float)hv[0], h1 = (float)hv[1], h2v = (float)hv[2], h3 = (float)hv[3];
    float s1 = h0 + h1 + h2v + h3;
    float s2 = h0 * h0 + h1 * h1 + h2v * h2v + h3 * h3;
    float sv = h0 * v4[0] + h1 * v4[1] + h2v * v4[2] + h3 * v4[3];
#pragma unroll
    for (int m = 1; m < 64; m <<= 1) {
      s1 += __shfl_xor(s1, m, 64);
      s2 += __shfl_xor(s2, m, 64);
      sv += __shfl_xor(sv, m, 64);
    }
    if (lane == 0) {
      float mu = s1 * (1.0f / 256.0f);
      float var = s2 * (1.0f / 256.0f) - mu * mu;
      float is = rsqrtf(var + 1e-5f);
      smu[tt] = mu; sis[tt] = is;
      ssc[tt] = (sv - mu * Vsum) * is + Csum;
    }
  }
  __syncthreads();
  // softmax over 512 scores
  float a0 = ssc[tid], a1 = ssc[tid + 256];
  float mx = fmaxf(a0, a1);
#pragma unroll
  for (int m = 1; m < 64; m <<= 1) mx = fmaxf(mx, __shfl_xor(mx, m, 64));
  if (lane == 0) red[wave] = mx;
  __syncthreads();
  mx = fmaxf(fmaxf(red[0], red[1]), fmaxf(red[2], red[3]));
  __syncthreads();  // protect red reuse
  float p0 = exp2f((a0 - mx) * 1.44269504f);
  float p1 = exp2f((a1 - mx) * 1.44269504f);
  float ps = p0 + p1;
  float pm = p0 * smu[tid] * sis[tid] + p1 * smu[tid + 256] * sis[tid + 256];
#pragma unroll
  for (int m = 1; m < 64; m <<= 1) { ps += __shfl_xor(ps, m, 64); pm += __shfl_xor(pm, m, 64); }
  if (lane == 0) { red[wave] = ps; red[8 + wave] = pm; }
  __syncthreads();
  const float S = red[0] + red[1] + red[2] + red[3];
  const float PM = (red[8] + red[9] + red[10] + red[11]) / S;
  ssc[tid] = p0 / S * sis[tid];          // alpha_t
  ssc[tid + 256] = p1 / S * sis[tid + 256];
  __syncthreads();
  // pass 2: attended_j = lnw_j*(sum_t alpha_t h_tj - PM) + lnb_j
  float acc = 0.f;
  for (int t = 0; t < 512; ++t) acc += ssc[t] * (float)hb[(size_t)t * 256 + tid];
  float att = lnw[tid] * (acc - PM) + lnb[tid];
  att_out[b * 256 + tid] = (f16)att;
}

// ---------------- launch ----------------

extern "C" void kernel_launch(void* const* d_in, const int* in_sizes, int n_in,
                              void* d_out, int out_size, void* d_ws, size_t ws_size,
                              hipStream_t stream) {
  (void)in_sizes; (void)n_in; (void)out_size; (void)ws_size;
  const float* x    = (const float*)d_in[0];
  const float* wih0 = (const float*)d_in[1];
  const float* whh0 = (const float*)d_in[2];
  const float* bih0 = (const float*)d_in[3];
  const float* bhh0 = (const float*)d_in[4];
  const float* wih1 = (const float*)d_in[5];
  const float* whh1 = (const float*)d_in[6];
  const float* bih1 = (const float*)d_in[7];
  const float* bhh1 = (const float*)d_in[8];
  const float* lnw  = (const float*)d_in[9];
  const float* lnb  = (const float*)d_in[10];
  const float* aw   = (const float*)d_in[11];
  const float* fcw  = (const float*)d_in[12];
  const float* fcb  = (const float*)d_in[13];

  char* ws = (char*)d_ws;
  f16* x_h      = (f16*)(ws + 0);            // 50331648 B; region reused after GEMM0:
  f16* h1       = (f16*)(ws + 0);            //   h1: 16777216 B
  f16* h2       = (f16*)(ws + 16777216);     //   h2: 16777216 B
  f16* wih0_h   = (f16*)(ws + 50331648);     // 1572864
  f16* wih1_h   = (f16*)(ws + 51904512);     // 524288
  f16* fcw_h    = (f16*)(ws + 52428800);     // 15627264
  uint32_t* wq0 = (uint32_t*)(ws + 68056064);// 262144
  uint32_t* wq1 = (uint32_t*)(ws + 68318208);// 262144
  float* qmul0  = (float*)(ws + 68580352);   // 4096
  float* dmul0  = (float*)(ws + 68584448);   // 4096
  float* qmul1  = (float*)(ws + 68588544);   // 4096
  float* dmul1  = (float*)(ws + 68592640);   // 4096
  float* bsum0  = (float*)(ws + 69104640);   // 4096
  float* bsum1  = (float*)(ws + 69108736);   // 4096
  f16* att_h    = (f16*)(ws + 69112832);     // 32768
  f16* xg       = (f16*)(ws + 69145600);     // 67108864 (shared by both layers)

  f32_to_f16_kernel<<<4096, 256, 0, stream>>>(x, x_h, 25165824 / 4);
  f32_to_f16_kernel<<<768, 256, 0, stream>>>(wih0, wih0_h, 786432 / 4);
  f32_to_f16_kernel<<<256, 256, 0, stream>>>(wih1, wih1_h, 262144 / 4);
  f32_to_f16_kernel<<<2048, 256, 0, stream>>>(fcw, fcw_h, 7813632 / 4);
  addvec_kernel<<<4, 256, 0, stream>>>(bih0, bhh0, bsum0, 1024);
  addvec_kernel<<<4, 256, 0, stream>>>(bih1, bhh1, bsum1, 1024);
  rowscale_kernel<<<16, 256, 0, stream>>>(whh0, qmul0, dmul0);
  rowscale_kernel<<<16, 256, 0, stream>>>(whh1, qmul1, dmul1);
  wq8_kernel<<<256, 256, 0, stream>>>(whh0, qmul0, wq0);
  wq8_kernel<<<256, 256, 0, stream>>>(whh1, qmul1, wq1);

  // layer 0: xg0 = x @ w_ih0^T + (b_ih0 + b_hh0)
  gemm_bt_kernel<0><<<dim3(8, 256), 256, 0, stream>>>(x_h, wih0_h, bsum0, xg, 32768, 1024, 768);
  lstm_rec_kernel<<<64, 512, 0, stream>>>(xg, (const u32x4*)wq0, dmul0, h1, 512);
  // layer 1
  gemm_bt_kernel<0><<<dim3(8, 256), 256, 0, stream>>>(h1, wih1_h, bsum1, xg, 32768, 1024, 256);
  lstm_rec_kernel<<<64, 512, 0, stream>>>(xg, (const u32x4*)wq1, dmul1, h2, 512);
  // LN + attention pooling
  ln_attn_kernel<<<64, 256, 0, stream>>>(h2, lnw, lnb, aw, att_h);
  // FC: out = attended @ fc_w^T + fc_b  (fp32 out)
  gemm_bt_kernel<1><<<dim3(239, 1), 256, 0, stream>>>(att_h, fcw_h, fcb, d_out, 64, 30522, 256);
}

// Round 13
// 1756.721 us; speedup vs baseline: 1.7016x; 1.0053x over previous
//
#include <hip/hip_runtime.h>
#include <cstdint>

typedef _Float16 f16;
using f16x2 = __attribute__((ext_vector_type(2))) _Float16;
using f16x4 = __attribute__((ext_vector_type(4))) _Float16;
using f16x8 = __attribute__((ext_vector_type(8))) _Float16;
using f32x4 = __attribute__((ext_vector_type(4))) float;
using u32x4 = __attribute__((ext_vector_type(4))) uint32_t;
using i32x4 = __attribute__((ext_vector_type(4))) int;

#define GLB_PTR(p) ((const __attribute__((address_space(1))) void*)(p))
#define LDS_PTR(p) ((__attribute__((address_space(3))) void*)(p))

// Newton-refined reciprocal: <=1 ulp at rcp + 2 fma (proven R9).
__device__ __forceinline__ float rcp_nr(float x) {
  float r = __builtin_amdgcn_rcpf(x);
  return fmaf(fmaf(-x, r, 1.0f), r, r);
}
__device__ __forceinline__ float sigmoidf_(float x) {
  float e = exp2f(-x * 1.44269504088896f);
  return rcp_nr(1.0f + e);
}
__device__ __forceinline__ float tanhf_(float x) {
  float e = exp2f(x * 2.88539008177793f);   // exp(2x)
  return 1.0f - 2.0f * rcp_nr(e + 1.0f);
}

// i8 MFMA, B operand + accumulator pinned in AGPR (zero-move weight reads).
__device__ __forceinline__ void mfma_i8(i32x4& d, u32x4 a, u32x4 b) {
  asm("v_mfma_i32_16x16x64_i8 %0, %1, %2, %0"
      : "+a"(d)
      : "v"(a), "a"(b));
}

// ---------------- conversion / prep kernels ----------------

__global__ void f32_to_f16_kernel(const float* __restrict__ in, f16* __restrict__ out, long n4) {
  long stride = (long)gridDim.x * blockDim.x;
  for (long i = blockIdx.x * (long)blockDim.x + threadIdx.x; i < n4; i += stride) {
    f32x4 v = *(const f32x4*)(in + i * 4);
    f16x4 h;
    h[0] = (f16)v[0]; h[1] = (f16)v[1]; h[2] = (f16)v[2]; h[3] = (f16)v[3];
    *(f16x4*)(out + i * 4) = h;
  }
}

__global__ void addvec_kernel(const float* __restrict__ a, const float* __restrict__ b,
                              float* __restrict__ o, int n) {
  int i = blockIdx.x * blockDim.x + threadIdx.x;
  if (i < n) o[i] = a[i] + b[i];
}

// Per-gate-row symmetric int8 scales: qmul[r]=127/max|W_r|, dmul[r]=max|W_r|/127^2.
__global__ __launch_bounds__(256) void rowscale_kernel(const float* __restrict__ whh,
                                                       float* __restrict__ qmul,
                                                       float* __restrict__ dmul) {
  const int wv = (blockIdx.x * 256 + threadIdx.x) >> 6;  // global wave 0..63
  const int lane = threadIdx.x & 63;
  for (int rr = 0; rr < 16; ++rr) {
    int r = wv * 16 + rr;
    f32x4 v = *(const f32x4*)(whh + r * 256 + lane * 4);
    float m = fmaxf(fmaxf(fabsf(v[0]), fabsf(v[1])), fmaxf(fabsf(v[2]), fabsf(v[3])));
#pragma unroll
    for (int s = 1; s < 64; s <<= 1) m = fmaxf(m, __shfl_xor(m, s, 64));
    if (lane == 0) {
      float sr = fmaxf(m, 1e-8f);
      qmul[r] = 127.0f / sr;
      dmul[r] = sr / 16129.0f;
    }
  }
}

// int8 B-fragment prep for v_mfma_i32_16x16x64_i8 (R7-proven k-map).
// dword i = ((t*4 + c)*64 + l)*4 + d ; byte e holds
// Wq[r = t*16 + (l&15)][k = c*64 + ((l>>4)&3)*16 + d*4 + e].
__global__ void wq8_kernel(const float* __restrict__ whh, const float* __restrict__ qmul,
                           uint32_t* __restrict__ wq) {
  int i = blockIdx.x * blockDim.x + threadIdx.x;  // 65536 threads
  int d = i & 3, l = (i >> 2) & 63, c = (i >> 8) & 3, t = i >> 10;
  int r = t * 16 + (l & 15);
  int k0 = c * 64 + ((l >> 4) & 3) * 16 + d * 4;
  float qm = qmul[r];
  uint32_t out = 0;
#pragma unroll
  for (int e = 0; e < 4; ++e) {
    int q = __float2int_rn(whh[r * 256 + k0 + e] * qm);
    q = min(127, max(-127, q));
    out |= ((uint32_t)(uint8_t)(int8_t)q) << (8 * e);
  }
  wq[i] = out;
}

// ---------------- GEMM: C[m,n] = sum_k A[m,k]*B[n,k] + bias[n] ----------------
// A [M,K] f16 row-major, B [N,K] f16 row-major. 128x128 tile, BK=32, 256 thr.
// R13: staging via global_load_lds width=16 (guide m93->m97: removes the VGPR
// round-trip). LDS chunk c = wave*64+lane at byte c*16 == HW's uniform-base +
// lane*16 pattern, so the bytes land identically to the old per-thread stores;
// fragments/MFMA/epilogue unchanged -> bit-identical results.

template <int OUTF32>
__global__ __launch_bounds__(256) void gemm_bt_kernel(
    const f16* __restrict__ A, const f16* __restrict__ B,
    const float* __restrict__ bias, void* __restrict__ Cout,
    int M, int N, int K) {
  __shared__ __align__(16) f16 Al[128 * 32];
  __shared__ __align__(16) f16 Bl[128 * 32];
  const int tid = threadIdx.x;
  const int lane = tid & 63, wave = tid >> 6;
  const int bn = blockIdx.x, bm = blockIdx.y;
  const int qm = (wave >> 1) * 64, qn = (wave & 1) * 64;

  f32x4 acc[4][4];
#pragma unroll
  for (int i = 0; i < 4; ++i)
#pragma unroll
    for (int j = 0; j < 4; ++j) acc[i][j] = (f32x4){0.f, 0.f, 0.f, 0.f};

  const int c0 = tid, c1 = 256 + tid;
  const int row0 = c0 >> 2, off0 = c0 & 3;
  const int row1 = c1 >> 2, off1 = c1 & 3;
  const int gmA0 = min(bm * 128 + row0, M - 1);
  const int gmA1 = min(bm * 128 + row1, M - 1);
  const int gnB0 = min(bn * 128 + row0, N - 1);
  const int gnB1 = min(bn * 128 + row1, N - 1);

  // wave-uniform LDS bases; HW writes base + lane*16
  f16* ldsA0 = &Al[(wave * 64) * 8];
  f16* ldsA1 = &Al[(256 + wave * 64) * 8];
  f16* ldsB0 = &Bl[(wave * 64) * 8];
  f16* ldsB1 = &Bl[(256 + wave * 64) * 8];

  for (int k0 = 0; k0 < K; k0 += 32) {
    __syncthreads();  // previous iteration's LDS frag reads done
    __builtin_amdgcn_global_load_lds(GLB_PTR(A + (size_t)gmA0 * K + k0 + off0 * 8),
                                     LDS_PTR(ldsA0), 16, 0, 0);
    __builtin_amdgcn_global_load_lds(GLB_PTR(A + (size_t)gmA1 * K + k0 + off1 * 8),
                                     LDS_PTR(ldsA1), 16, 0, 0);
    __builtin_amdgcn_global_load_lds(GLB_PTR(B + (size_t)gnB0 * K + k0 + off0 * 8),
                                     LDS_PTR(ldsB0), 16, 0, 0);
    __builtin_amdgcn_global_load_lds(GLB_PTR(B + (size_t)gnB1 * K + k0 + off1 * 8),
                                     LDS_PTR(ldsB1), 16, 0, 0);
    asm volatile("s_waitcnt vmcnt(0)" ::: "memory");
    __syncthreads();
    f16x8 af[4], bf[4];
#pragma unroll
    for (int mt = 0; mt < 4; ++mt)
      af[mt] = *(const f16x8*)&Al[(qm + mt * 16 + (lane & 15)) * 32 + (lane >> 4) * 8];
#pragma unroll
    for (int nt = 0; nt < 4; ++nt)
      bf[nt] = *(const f16x8*)&Bl[(qn + nt * 16 + (lane & 15)) * 32 + (lane >> 4) * 8];
#pragma unroll
    for (int mt = 0; mt < 4; ++mt)
#pragma unroll
      for (int nt = 0; nt < 4; ++nt)
        acc[mt][nt] = __builtin_amdgcn_mfma_f32_16x16x32_f16(af[mt], bf[nt], acc[mt][nt], 0, 0, 0);
  }

#pragma unroll
  for (int mt = 0; mt < 4; ++mt)
#pragma unroll
    for (int nt = 0; nt < 4; ++nt)
#pragma unroll
      for (int j = 0; j < 4; ++j) {
        int gm = bm * 128 + qm + mt * 16 + (lane >> 4) * 4 + j;
        int gn = bn * 128 + qn + nt * 16 + (lane & 15);
        if (gm < M && gn < N) {
          float v = acc[mt][nt][j] + bias[gn];
          if (OUTF32)
            ((float*)Cout)[(size_t)gm * N + gn] = v;
          else
            ((f16*)Cout)[(size_t)gm * N + gn] = (f16)v;
        }
      }
}

// ---------------- persistent LSTM recurrence (int8 MFMA, two-level h) ----------------
// R9 EXACT TEXT (proven: 729 us/layer, absmax 0.0098). 64 blocks x 512 threads
// (8 waves), __launch_bounds__(512,2). 8 weight tiles/wave in AGPR (128 + 32 acc =
// 160 a-regs — the proven-safe envelope; R8/R12's restructures beyond it broke).
// Two-level h: A row0 = h_hi (h*127), row1 = h_lo (residual); one MFMA yields
// D row0 = Wq.h_hi, D row1 = Wq.h_lo; gate = dmul*D0 + (dmul/127)*D1 + xg.
// Per step: 4 ds_read_b128 A-frags + 32 asm MFMAs, zero weight loads, xg prefetch,
// NR-rcp activations, 1 barrier (lgkmcnt-only; global h stores never drained).

__global__ __launch_bounds__(512, 2) void lstm_rec_kernel(
    const f16* __restrict__ xg,          // [B*T, 1024], biases included
    const u32x4* __restrict__ wq,        // [64 t][4 c][64 l] u32x4 int8 frags
    const float* __restrict__ dmul,      // [1024] per-row dequant scale
    f16* __restrict__ h_out,             // [B*T, 256]
    int T) {
  __shared__ __align__(16) uint8_t h8[2][512];   // [hi 256 | lo 256], double-buffered
  const int b = blockIdx.x;
  const int tid = threadIdx.x;
  const int w = tid >> 6, lane = tid & 63;
  const int l15 = lane & 15, kg = (lane >> 4) & 3;
  const int base = w * 16 + l15;        // row(j) = base + 128*j ; uA=base, uB=base+128
  const int uA = base, uB = base + 128;
  const int asel = (l15 == 1) ? 256 : 0;  // row1 lanes read the lo slice

  // all 8 tiles -> AGPR (used only via "a" asm operands)
  u32x4 wt[8][4];
#pragma unroll
  for (int j = 0; j < 8; ++j)
#pragma unroll
    for (int c = 0; c < 4; ++c)
      wt[j][c] = wq[((w + 8 * j) * 4 + c) * 64 + lane];
  float sc[8], sc2[8];
#pragma unroll
  for (int j = 0; j < 8; ++j) {
    sc[j] = dmul[base + 128 * j];
    sc2[j] = sc[j] * (1.0f / 127.0f);
  }

  if (tid < 256) ((uint32_t*)h8)[tid] = 0;   // zero both buffers (1 KB)
  float cA = 0.f, cB = 0.f;
  __syncthreads();

  const f16* xt = xg + (size_t)b * T * 1024;
  f16* hob = h_out + (size_t)b * T * 256;

  // prologue: prefetch step-0 xg contributions
  f16 xc[8];
#pragma unroll
  for (int j = 0; j < 8; ++j) xc[j] = xt[base + 128 * j];

  for (int t = 0; t < T; ++t) {
    // consume prefetched xg; issue next step's loads (hidden under this step)
    float xv[8];
#pragma unroll
    for (int j = 0; j < 8; ++j) xv[j] = (float)xc[j];
    const f16* xn = (t + 1 < T) ? xt + 1024 : xt;
#pragma unroll
    for (int j = 0; j < 8; ++j) xc[j] = xn[base + 128 * j];

    i32x4 z = (i32x4){0, 0, 0, 0};
    i32x4 a0 = z, a1 = z, a2 = z, a3 = z, a4 = z, a5 = z, a6 = z, a7 = z;
    const uint8_t* hq = h8[t & 1] + asel;
#pragma unroll
    for (int c = 0; c < 4; ++c) {
      u32x4 afr = *(const u32x4*)(hq + c * 64 + kg * 16);   // row0=hi, row1=lo
      mfma_i8(a0, afr, wt[0][c]);
      mfma_i8(a1, afr, wt[1][c]);
      mfma_i8(a2, afr, wt[2][c]);
      mfma_i8(a3, afr, wt[3][c]);
      mfma_i8(a4, afr, wt[4][c]);
      mfma_i8(a5, afr, wt[5][c]);
      mfma_i8(a6, afr, wt[6][c]);
      mfma_i8(a7, afr, wt[7][c]);
    }
    // dequant + activation (valid on kg=0 lanes; others compute discarded garbage)
    float gI_A = (float)a0[0] * sc[0] + (float)a0[1] * sc2[0] + xv[0];
    float gI_B = (float)a1[0] * sc[1] + (float)a1[1] * sc2[1] + xv[1];
    float gF_A = (float)a2[0] * sc[2] + (float)a2[1] * sc2[2] + xv[2];
    float gF_B = (float)a3[0] * sc[3] + (float)a3[1] * sc2[3] + xv[3];
    float gG_A = (float)a4[0] * sc[4] + (float)a4[1] * sc2[4] + xv[4];
    float gG_B = (float)a5[0] * sc[5] + (float)a5[1] * sc2[5] + xv[5];
    float gO_A = (float)a6[0] * sc[6] + (float)a6[1] * sc2[6] + xv[6];
    float gO_B = (float)a7[0] * sc[7] + (float)a7[1] * sc2[7] + xv[7];
    float iA = sigmoidf_(gI_A), iB = sigmoidf_(gI_B);
    float fA = sigmoidf_(gF_A), fB = sigmoidf_(gF_B);
    float gA = tanhf_(gG_A),   gB = tanhf_(gG_B);
    float oA = sigmoidf_(gO_A), oB = sigmoidf_(gO_B);
    cA = fA * cA + iA * gA;
    cB = fB * cB + iB * gB;
    float hA = oA * tanhf_(cA);
    float hB = oB * tanhf_(cB);
    // two-level quantize: hi = round(h*127); lo = round((h - hi/127)*16129)
    int hiA = __float2int_rn(hA * 127.0f);
    int hiB = __float2int_rn(hB * 127.0f);
    int loA = __float2int_rn(fmaf((float)hiA, -127.0f, hA * 16129.0f));
    int loB = __float2int_rn(fmaf((float)hiB, -127.0f, hB * 16129.0f));
    uint8_t* hn = (uint8_t*)h8[(t + 1) & 1];
    if (lane < 16) {
      hn[uA] = (uint8_t)(int8_t)hiA;
      hn[uB] = (uint8_t)(int8_t)hiB;
      hn[256 + uA] = (uint8_t)(int8_t)loA;
      hn[256 + uB] = (uint8_t)(int8_t)loB;
      hob[(size_t)t * 256 + uA] = (f16)hA;   // global h (vmcnt floats, never drained)
      hob[(size_t)t * 256 + uB] = (f16)hB;
    }
    xt += 1024;
    asm volatile("s_waitcnt lgkmcnt(0)" ::: "memory");  // h8 writes visible
    __builtin_amdgcn_s_barrier();
    __builtin_amdgcn_sched_barrier(0);
  }
}

// ---------------- fused LayerNorm + attention pooling ----------------
// one block per batch, 256 threads.

__global__ __launch_bounds__(256) void ln_attn_kernel(
    const f16* __restrict__ h2, const float* __restrict__ lnw,
    const float* __restrict__ lnb, const float* __restrict__ aw,
    f16* __restrict__ att_out) {
  const int b = blockIdx.x, tid = threadIdx.x;
  const int lane = tid & 63, wave = tid >> 6;
  __shared__ float smu[512], sis[512], ssc[512];
  __shared__ float vbuf[256];
  __shared__ float red[16];

  float vj = aw[tid] * lnw[tid];
  float uj = aw[tid] * lnb[tid];
  vbuf[tid] = vj;
  float rv = vj, ru = uj;
#pragma unroll
  for (int m = 1; m < 64; m <<= 1) { rv += __shfl_xor(rv, m, 64); ru += __shfl_xor(ru, m, 64); }
  if (lane == 0) { red[wave] = rv; red[4 + wave] = ru; }
  __syncthreads();
  const float Vsum = red[0] + red[1] + red[2] + red[3];
  const float Csum = red[4] + red[5] + red[6] + red[7];
  const f32x4 v4 = *(const f32x4*)&vbuf[lane * 4];
  const f16* hb = h2 + (size_t)b * 512 * 256;

  for (int tt = wave; tt < 512; tt += 4) {
    f16x4 hv = *(const f16x4*)(hb + (size_t)tt * 256 + lane * 4);
    float h0 = (float)hv[0], h1 = (float)hv[1], h2v = (float)hv[2], h3 = (float)hv[3];
    float s1 = h0 + h1 + h2v + h3;
    float s2 = h0 * h0 + h1 * h1 + h2v * h2v + h3 * h3;
    float sv = h0 * v4[0] + h1 * v4[1] + h2v * v4[2] + h3 * v4[3];
#pragma unroll
    for (int m = 1; m < 64; m <<= 1) {
      s1 += __shfl_xor(s1, m, 64);
      s2 += __shfl_xor(s2, m, 64);
      sv += __shfl_xor(sv, m, 64);
    }
    if (lane == 0) {
      float mu = s1 * (1.0f / 256.0f);
      float var = s2 * (1.0f / 256.0f) - mu * mu;
      float is = rsqrtf(var + 1e-5f);
      smu[tt] = mu; sis[tt] = is;
      ssc[tt] = (sv - mu * Vsum) * is + Csum;
    }
  }
  __syncthreads();
  // softmax over 512 scores
  float a0 = ssc[tid], a1 = ssc[tid + 256];
  float mx = fmaxf(a0, a1);
#pragma unroll
  for (int m = 1; m < 64; m <<= 1) mx = fmaxf(mx, __shfl_xor(mx, m, 64));
  if (lane == 0) red[wave] = mx;
  __syncthreads();
  mx = fmaxf(fmaxf(red[0], red[1]), fmaxf(red[2], red[3]));
  __syncthreads();  // protect red reuse
  float p0 = exp2f((a0 - mx) * 1.44269504f);
  float p1 = exp2f((a1 - mx) * 1.44269504f);
  float ps = p0 + p1;
  float pm = p0 * smu[tid] * sis[tid] + p1 * smu[tid + 256] * sis[tid + 256];
#pragma unroll
  for (int m = 1; m < 64; m <<= 1) { ps += __shfl_xor(ps, m, 64); pm += __shfl_xor(pm, m, 64); }
  if (lane == 0) { red[wave] = ps; red[8 + wave] = pm; }
  __syncthreads();
  const float S = red[0] + red[1] + red[2] + red[3];
  const float PM = (red[8] + red[9] + red[10] + red[11]) / S;
  ssc[tid] = p0 / S * sis[tid];          // alpha_t
  ssc[tid + 256] = p1 / S * sis[tid + 256];
  __syncthreads();
  // pass 2: attended_j = lnw_j*(sum_t alpha_t h_tj - PM) + lnb_j
  float acc = 0.f;
  for (int t = 0; t < 512; ++t) acc += ssc[t] * (float)hb[(size_t)t * 256 + tid];
  float att = lnw[tid] * (acc - PM) + lnb[tid];
  att_out[b * 256 + tid] = (f16)att;
}

// ---------------- launch ----------------

extern "C" void kernel_launch(void* const* d_in, const int* in_sizes, int n_in,
                              void* d_out, int out_size, void* d_ws, size_t ws_size,
                              hipStream_t stream) {
  (void)in_sizes; (void)n_in; (void)out_size; (void)ws_size;
  const float* x    = (const float*)d_in[0];
  const float* wih0 = (const float*)d_in[1];
  const float* whh0 = (const float*)d_in[2];
  const float* bih0 = (const float*)d_in[3];
  const float* bhh0 = (const float*)d_in[4];
  const float* wih1 = (const float*)d_in[5];
  const float* whh1 = (const float*)d_in[6];
  const float* bih1 = (const float*)d_in[7];
  const float* bhh1 = (const float*)d_in[8];
  const float* lnw  = (const float*)d_in[9];
  const float* lnb  = (const float*)d_in[10];
  const float* aw   = (const float*)d_in[11];
  const float* fcw  = (const float*)d_in[12];
  const float* fcb  = (const float*)d_in[13];

  char* ws = (char*)d_ws;
  f16* x_h      = (f16*)(ws + 0);            // 50331648 B; region reused after GEMM0:
  f16* h1       = (f16*)(ws + 0);            //   h1: 16777216 B
  f16* h2       = (f16*)(ws + 16777216);     //   h2: 16777216 B
  f16* wih0_h   = (f16*)(ws + 50331648);     // 1572864
  f16* wih1_h   = (f16*)(ws + 51904512);     // 524288
  f16* fcw_h    = (f16*)(ws + 52428800);     // 15627264
  uint32_t* wq0 = (uint32_t*)(ws + 68056064);// 262144
  uint32_t* wq1 = (uint32_t*)(ws + 68318208);// 262144
  float* qmul0  = (float*)(ws + 68580352);   // 4096
  float* dmul0  = (float*)(ws + 68584448);   // 4096
  float* qmul1  = (float*)(ws + 68588544);   // 4096
  float* dmul1  = (float*)(ws + 68592640);   // 4096
  float* bsum0  = (float*)(ws + 69104640);   // 4096
  float* bsum1  = (float*)(ws + 69108736);   // 4096
  f16* att_h    = (f16*)(ws + 69112832);     // 32768
  f16* xg       = (f16*)(ws + 69145600);     // 67108864 (shared by both layers)

  f32_to_f16_kernel<<<4096, 256, 0, stream>>>(x, x_h, 25165824 / 4);
  f32_to_f16_kernel<<<768, 256, 0, stream>>>(wih0, wih0_h, 786432 / 4);
  f32_to_f16_kernel<<<256, 256, 0, stream>>>(wih1, wih1_h, 262144 / 4);
  f32_to_f16_kernel<<<2048, 256, 0, stream>>>(fcw, fcw_h, 7813632 / 4);
  addvec_kernel<<<4, 256, 0, stream>>>(bih0, bhh0, bsum0, 1024);
  addvec_kernel<<<4, 256, 0, stream>>>(bih1, bhh1, bsum1, 1024);
  rowscale_kernel<<<16, 256, 0, stream>>>(whh0, qmul0, dmul0);
  rowscale_kernel<<<16, 256, 0, stream>>>(whh1, qmul1, dmul1);
  wq8_kernel<<<256, 256, 0, stream>>>(whh0, qmul0, wq0);
  wq8_kernel<<<256, 256, 0, stream>>>(whh1, qmul1, wq1);

  // layer 0: xg0 = x @ w_ih0^T + (b_ih0 + b_hh0)
  gemm_bt_kernel<0><<<dim3(8, 256), 256, 0, stream>>>(x_h, wih0_h, bsum0, xg, 32768, 1024, 768);
  lstm_rec_kernel<<<64, 512, 0, stream>>>(xg, (const u32x4*)wq0, dmul0, h1, 512);
  // layer 1
  gemm_bt_kernel<0><<<dim3(8, 256), 256, 0, stream>>>(h1, wih1_h, bsum1, xg, 32768, 1024, 256);
  lstm_rec_kernel<<<64, 512, 0, stream>>>(xg, (const u32x4*)wq1, dmul1, h2, 512);
  // LN + attention pooling
  ln_attn_kernel<<<64, 256, 0, stream>>>(h2, lnw, lnb, aw, att_h);
  // FC: out = attended @ fc_w^T + fc_b  (fp32 out)
  gemm_bt_kernel<1><<<dim3(239, 1), 256, 0, stream>>>(att_h, fcw_h, fcb, d_out, 64, 30522, 256);
}

// Round 14
// 1584.188 us; speedup vs baseline: 1.8869x; 1.1089x over previous
//
#include <hip/hip_runtime.h>
#include <cstdint>

typedef _Float16 f16;
using f16x2 = __attribute__((ext_vector_type(2))) _Float16;
using f16x4 = __attribute__((ext_vector_type(4))) _Float16;
using f16x8 = __attribute__((ext_vector_type(8))) _Float16;
using f32x4 = __attribute__((ext_vector_type(4))) float;
using u32x4 = __attribute__((ext_vector_type(4))) uint32_t;
using i32x4 = __attribute__((ext_vector_type(4))) int;

#define GLB_PTR(p) ((const __attribute__((address_space(1))) void*)(p))
#define LDS_PTR(p) ((__attribute__((address_space(3))) void*)(p))

// Newton-refined reciprocal: <=1 ulp at rcp + 2 fma (proven R9).
__device__ __forceinline__ float rcp_nr(float x) {
  float r = __builtin_amdgcn_rcpf(x);
  return fmaf(fmaf(-x, r, 1.0f), r, r);
}
__device__ __forceinline__ float sigmoidf_(float x) {
  float e = exp2f(-x * 1.44269504088896f);
  return rcp_nr(1.0f + e);
}
__device__ __forceinline__ float tanhf_(float x) {
  float e = exp2f(x * 2.88539008177793f);   // exp(2x)
  return 1.0f - 2.0f * rcp_nr(e + 1.0f);
}

// i8 MFMA. B (weights) pinned in AGPR; accumulator in VGPR (R14: "+a"->"+v",
// so dequant reads accs directly — no v_accvgpr_read round-trip). Zero-C form
// (proven R10/R11) avoids 32 zero-init moves per step.
__device__ __forceinline__ void mfma_i8(i32x4& d, u32x4 a, u32x4 b) {
  asm("v_mfma_i32_16x16x64_i8 %0, %1, %2, %0"
      : "+v"(d)
      : "v"(a), "a"(b));
}
__device__ __forceinline__ void mfma_i8_z(i32x4& d, u32x4 a, u32x4 b, const i32x4& zc) {
  asm("v_mfma_i32_16x16x64_i8 %0, %1, %2, %3"
      : "=v"(d)
      : "v"(a), "a"(b), "v"(zc));
}

// ---------------- fused prep kernels (R14: launch-count reduction) ----------------

// all four f32->f16 conversions in one grid-stride kernel (region-split on index)
__global__ void convert_all_kernel(const float* __restrict__ x, f16* __restrict__ x_h,
                                   const float* __restrict__ w0, f16* __restrict__ w0_h,
                                   const float* __restrict__ w1, f16* __restrict__ w1_h,
                                   const float* __restrict__ fw, f16* __restrict__ fw_h) {
  const long N0 = 6291456, N1 = N0 + 196608, N2 = N1 + 65536, N3 = N2 + 1953408;
  long stride = (long)gridDim.x * blockDim.x;
  for (long i = blockIdx.x * (long)blockDim.x + threadIdx.x; i < N3; i += stride) {
    const float* in; f16* out; long j;
    if (i < N0)      { in = x;  out = x_h;  j = i; }
    else if (i < N1) { in = w0; out = w0_h; j = i - N0; }
    else if (i < N2) { in = w1; out = w1_h; j = i - N1; }
    else             { in = fw; out = fw_h; j = i - N2; }
    f32x4 v = *(const f32x4*)(in + j * 4);
    f16x4 h;
    h[0] = (f16)v[0]; h[1] = (f16)v[1]; h[2] = (f16)v[2]; h[3] = (f16)v[3];
    *(f16x4*)(out + j * 4) = h;
  }
}

// both bias sums in one kernel
__global__ void addvec2_kernel(const float* __restrict__ a0, const float* __restrict__ b0,
                               float* __restrict__ o0,
                               const float* __restrict__ a1, const float* __restrict__ b1,
                               float* __restrict__ o1) {
  int i = blockIdx.x * blockDim.x + threadIdx.x;  // 2048 threads
  if (i < 1024) o0[i] = a0[i] + b0[i];
  else if (i < 2048) o1[i - 1024] = a1[i - 1024] + b1[i - 1024];
}

// Per-gate-row symmetric int8 scales for both weights (R7-proven math).
__global__ __launch_bounds__(256) void rowscale2_kernel(
    const float* __restrict__ whh0, float* __restrict__ qmul0, float* __restrict__ dmul0,
    const float* __restrict__ whh1, float* __restrict__ qmul1, float* __restrict__ dmul1) {
  int blk = blockIdx.x;  // 32 blocks: 0-15 -> whh0, 16-31 -> whh1
  const float* whh; float* qmul; float* dmul;
  if (blk < 16) { whh = whh0; qmul = qmul0; dmul = dmul0; }
  else          { whh = whh1; qmul = qmul1; dmul = dmul1; blk -= 16; }
  const int wv = (blk * 256 + (int)threadIdx.x) >> 6;  // wave 0..63
  const int lane = threadIdx.x & 63;
  for (int rr = 0; rr < 16; ++rr) {
    int r = wv * 16 + rr;
    f32x4 v = *(const f32x4*)(whh + r * 256 + lane * 4);
    float m = fmaxf(fmaxf(fabsf(v[0]), fabsf(v[1])), fmaxf(fabsf(v[2]), fabsf(v[3])));
#pragma unroll
    for (int s = 1; s < 64; s <<= 1) m = fmaxf(m, __shfl_xor(m, s, 64));
    if (lane == 0) {
      float sr = fmaxf(m, 1e-8f);
      qmul[r] = 127.0f / sr;
      dmul[r] = sr / 16129.0f;
    }
  }
}

// int8 B-fragment prep for both weights (R7-proven k-map).
// dword i = ((t*4 + c)*64 + l)*4 + d ; byte e holds
// Wq[r = t*16 + (l&15)][k = c*64 + ((l>>4)&3)*16 + d*4 + e].
__global__ void wq82_kernel(const float* __restrict__ whh0, const float* __restrict__ qmul0,
                            uint32_t* __restrict__ wq0,
                            const float* __restrict__ whh1, const float* __restrict__ qmul1,
                            uint32_t* __restrict__ wq1) {
  int i = blockIdx.x * blockDim.x + threadIdx.x;  // 131072 threads
  const float* whh; const float* qmul; uint32_t* wq;
  if (i < 65536) { whh = whh0; qmul = qmul0; wq = wq0; }
  else           { whh = whh1; qmul = qmul1; wq = wq1; i -= 65536; }
  int d = i & 3, l = (i >> 2) & 63, c = (i >> 8) & 3, t = i >> 10;
  int r = t * 16 + (l & 15);
  int k0 = c * 64 + ((l >> 4) & 3) * 16 + d * 4;
  float qm = qmul[r];
  uint32_t out = 0;
#pragma unroll
  for (int e = 0; e < 4; ++e) {
    int q = __float2int_rn(whh[r * 256 + k0 + e] * qm);
    q = min(127, max(-127, q));
    out |= ((uint32_t)(uint8_t)(int8_t)q) << (8 * e);
  }
  wq[i] = out;
}

// ---------------- GEMM: C[m,n] = sum_k A[m,k]*B[n,k] + bias[n] ----------------
// A [M,K] f16 row-major, B [N,K] f16 row-major. 128x128 tile, BK=32, 256 thr.
// Staging via global_load_lds width=16 (R13-proven).

template <int OUTF32>
__global__ __launch_bounds__(256) void gemm_bt_kernel(
    const f16* __restrict__ A, const f16* __restrict__ B,
    const float* __restrict__ bias, void* __restrict__ Cout,
    int M, int N, int K) {
  __shared__ __align__(16) f16 Al[128 * 32];
  __shared__ __align__(16) f16 Bl[128 * 32];
  const int tid = threadIdx.x;
  const int lane = tid & 63, wave = tid >> 6;
  const int bn = blockIdx.x, bm = blockIdx.y;
  const int qm = (wave >> 1) * 64, qn = (wave & 1) * 64;

  f32x4 acc[4][4];
#pragma unroll
  for (int i = 0; i < 4; ++i)
#pragma unroll
    for (int j = 0; j < 4; ++j) acc[i][j] = (f32x4){0.f, 0.f, 0.f, 0.f};

  const int c0 = tid, c1 = 256 + tid;
  const int row0 = c0 >> 2, off0 = c0 & 3;
  const int row1 = c1 >> 2, off1 = c1 & 3;
  const int gmA0 = min(bm * 128 + row0, M - 1);
  const int gmA1 = min(bm * 128 + row1, M - 1);
  const int gnB0 = min(bn * 128 + row0, N - 1);
  const int gnB1 = min(bn * 128 + row1, N - 1);

  // wave-uniform LDS bases; HW writes base + lane*16
  f16* ldsA0 = &Al[(wave * 64) * 8];
  f16* ldsA1 = &Al[(256 + wave * 64) * 8];
  f16* ldsB0 = &Bl[(wave * 64) * 8];
  f16* ldsB1 = &Bl[(256 + wave * 64) * 8];

  for (int k0 = 0; k0 < K; k0 += 32) {
    __syncthreads();  // previous iteration's LDS frag reads done
    __builtin_amdgcn_global_load_lds(GLB_PTR(A + (size_t)gmA0 * K + k0 + off0 * 8),
                                     LDS_PTR(ldsA0), 16, 0, 0);
    __builtin_amdgcn_global_load_lds(GLB_PTR(A + (size_t)gmA1 * K + k0 + off1 * 8),
                                     LDS_PTR(ldsA1), 16, 0, 0);
    __builtin_amdgcn_global_load_lds(GLB_PTR(B + (size_t)gnB0 * K + k0 + off0 * 8),
                                     LDS_PTR(ldsB0), 16, 0, 0);
    __builtin_amdgcn_global_load_lds(GLB_PTR(B + (size_t)gnB1 * K + k0 + off1 * 8),
                                     LDS_PTR(ldsB1), 16, 0, 0);
    asm volatile("s_waitcnt vmcnt(0)" ::: "memory");
    __syncthreads();
    f16x8 af[4], bf[4];
#pragma unroll
    for (int mt = 0; mt < 4; ++mt)
      af[mt] = *(const f16x8*)&Al[(qm + mt * 16 + (lane & 15)) * 32 + (lane >> 4) * 8];
#pragma unroll
    for (int nt = 0; nt < 4; ++nt)
      bf[nt] = *(const f16x8*)&Bl[(qn + nt * 16 + (lane & 15)) * 32 + (lane >> 4) * 8];
#pragma unroll
    for (int mt = 0; mt < 4; ++mt)
#pragma unroll
      for (int nt = 0; nt < 4; ++nt)
        acc[mt][nt] = __builtin_amdgcn_mfma_f32_16x16x32_f16(af[mt], bf[nt], acc[mt][nt], 0, 0, 0);
  }

#pragma unroll
  for (int mt = 0; mt < 4; ++mt)
#pragma unroll
    for (int nt = 0; nt < 4; ++nt)
#pragma unroll
      for (int j = 0; j < 4; ++j) {
        int gm = bm * 128 + qm + mt * 16 + (lane >> 4) * 4 + j;
        int gn = bn * 128 + qn + nt * 16 + (lane & 15);
        if (gm < M && gn < N) {
          float v = acc[mt][nt][j] + bias[gn];
          if (OUTF32)
            ((float*)Cout)[(size_t)gm * N + gn] = v;
          else
            ((f16*)Cout)[(size_t)gm * N + gn] = (f16)v;
        }
      }
}

// ---------------- persistent LSTM recurrence (int8 MFMA, two-level h) ----------------
// R9-proven geometry (729 us/layer, absmax 0.0098): 64 blocks x 512 threads (8 waves),
// __launch_bounds__(512,2). 8 weight tiles/wave in AGPR (128 a-regs — proven-safe
// envelope). Two-level h: A row0 = h_hi (h*127), row1 = h_lo (residual); one MFMA
// yields D row0 = Wq.h_hi, D row1 = Wq.h_lo; gate = dmul*D0 + (dmul/127)*D1 + xg.
// R14 delta: accumulators in VGPR (mfma "+v"/"=v") + zero-C first chunk — removes
// the v_accvgpr_read feed into dequant and the 32 zero-init moves per step.
// Per step: 4 ds_read_b128 A-frags + 32 asm MFMAs, zero weight loads, xg prefetch,
// NR-rcp activations, 1 barrier (lgkmcnt-only; global h stores never drained).

__global__ __launch_bounds__(512, 2) void lstm_rec_kernel(
    const f16* __restrict__ xg,          // [B*T, 1024], biases included
    const u32x4* __restrict__ wq,        // [64 t][4 c][64 l] u32x4 int8 frags
    const float* __restrict__ dmul,      // [1024] per-row dequant scale
    f16* __restrict__ h_out,             // [B*T, 256]
    int T) {
  __shared__ __align__(16) uint8_t h8[2][512];   // [hi 256 | lo 256], double-buffered
  const int b = blockIdx.x;
  const int tid = threadIdx.x;
  const int w = tid >> 6, lane = tid & 63;
  const int l15 = lane & 15, kg = (lane >> 4) & 3;
  const int base = w * 16 + l15;        // row(j) = base + 128*j ; uA=base, uB=base+128
  const int uA = base, uB = base + 128;
  const int asel = (l15 == 1) ? 256 : 0;  // row1 lanes read the lo slice

  // all 8 tiles -> AGPR (used only via "a" asm operands)
  u32x4 wt[8][4];
#pragma unroll
  for (int j = 0; j < 8; ++j)
#pragma unroll
    for (int c = 0; c < 4; ++c)
      wt[j][c] = wq[((w + 8 * j) * 4 + c) * 64 + lane];
  float sc[8], sc2[8];
#pragma unroll
  for (int j = 0; j < 8; ++j) {
    sc[j] = dmul[base + 128 * j];
    sc2[j] = sc[j] * (1.0f / 127.0f);
  }

  if (tid < 256) ((uint32_t*)h8)[tid] = 0;   // zero both buffers (1 KB)
  float cA = 0.f, cB = 0.f;
  __syncthreads();

  const f16* xt = xg + (size_t)b * T * 1024;
  f16* hob = h_out + (size_t)b * T * 256;

  // prologue: prefetch step-0 xg contributions
  f16 xc[8];
#pragma unroll
  for (int j = 0; j < 8; ++j) xc[j] = xt[base + 128 * j];

  const i32x4 zc = (i32x4){0, 0, 0, 0};

  for (int t = 0; t < T; ++t) {
    // consume prefetched xg; issue next step's loads (hidden under this step)
    float xv[8];
#pragma unroll
    for (int j = 0; j < 8; ++j) xv[j] = (float)xc[j];
    const f16* xn = (t + 1 < T) ? xt + 1024 : xt;
#pragma unroll
    for (int j = 0; j < 8; ++j) xc[j] = xn[base + 128 * j];

    const uint8_t* hq = h8[t & 1] + asel;
    u32x4 afr0 = *(const u32x4*)(hq + 0 * 64 + kg * 16);   // row0=hi, row1=lo
    i32x4 a0, a1, a2, a3, a4, a5, a6, a7;
    mfma_i8_z(a0, afr0, wt[0][0], zc);
    mfma_i8_z(a1, afr0, wt[1][0], zc);
    mfma_i8_z(a2, afr0, wt[2][0], zc);
    mfma_i8_z(a3, afr0, wt[3][0], zc);
    mfma_i8_z(a4, afr0, wt[4][0], zc);
    mfma_i8_z(a5, afr0, wt[5][0], zc);
    mfma_i8_z(a6, afr0, wt[6][0], zc);
    mfma_i8_z(a7, afr0, wt[7][0], zc);
#pragma unroll
    for (int c = 1; c < 4; ++c) {
      u32x4 afr = *(const u32x4*)(hq + c * 64 + kg * 16);
      mfma_i8(a0, afr, wt[0][c]);
      mfma_i8(a1, afr, wt[1][c]);
      mfma_i8(a2, afr, wt[2][c]);
      mfma_i8(a3, afr, wt[3][c]);
      mfma_i8(a4, afr, wt[4][c]);
      mfma_i8(a5, afr, wt[5][c]);
      mfma_i8(a6, afr, wt[6][c]);
      mfma_i8(a7, afr, wt[7][c]);
    }
    // dequant + activation (valid on kg=0 lanes; others compute discarded garbage)
    float gI_A = (float)a0[0] * sc[0] + (float)a0[1] * sc2[0] + xv[0];
    float gI_B = (float)a1[0] * sc[1] + (float)a1[1] * sc2[1] + xv[1];
    float gF_A = (float)a2[0] * sc[2] + (float)a2[1] * sc2[2] + xv[2];
    float gF_B = (float)a3[0] * sc[3] + (float)a3[1] * sc2[3] + xv[3];
    float gG_A = (float)a4[0] * sc[4] + (float)a4[1] * sc2[4] + xv[4];
    float gG_B = (float)a5[0] * sc[5] + (float)a5[1] * sc2[5] + xv[5];
    float gO_A = (float)a6[0] * sc[6] + (float)a6[1] * sc2[6] + xv[6];
    float gO_B = (float)a7[0] * sc[7] + (float)a7[1] * sc2[7] + xv[7];
    float iA = sigmoidf_(gI_A), iB = sigmoidf_(gI_B);
    float fA = sigmoidf_(gF_A), fB = sigmoidf_(gF_B);
    float gA = tanhf_(gG_A),   gB = tanhf_(gG_B);
    float oA = sigmoidf_(gO_A), oB = sigmoidf_(gO_B);
    cA = fA * cA + iA * gA;
    cB = fB * cB + iB * gB;
    float hA = oA * tanhf_(cA);
    float hB = oB * tanhf_(cB);
    // two-level quantize: hi = round(h*127); lo = round((h - hi/127)*16129)
    int hiA = __float2int_rn(hA * 127.0f);
    int hiB = __float2int_rn(hB * 127.0f);
    int loA = __float2int_rn(fmaf((float)hiA, -127.0f, hA * 16129.0f));
    int loB = __float2int_rn(fmaf((float)hiB, -127.0f, hB * 16129.0f));
    uint8_t* hn = (uint8_t*)h8[(t + 1) & 1];
    if (lane < 16) {
      hn[uA] = (uint8_t)(int8_t)hiA;
      hn[uB] = (uint8_t)(int8_t)hiB;
      hn[256 + uA] = (uint8_t)(int8_t)loA;
      hn[256 + uB] = (uint8_t)(int8_t)loB;
      hob[(size_t)t * 256 + uA] = (f16)hA;   // global h (vmcnt floats, never drained)
      hob[(size_t)t * 256 + uB] = (f16)hB;
    }
    xt += 1024;
    asm volatile("s_waitcnt lgkmcnt(0)" ::: "memory");  // h8 writes visible
    __builtin_amdgcn_s_barrier();
    __builtin_amdgcn_sched_barrier(0);
  }
}

// ---------------- fused LayerNorm + attention pooling ----------------
// one block per batch, 256 threads.

__global__ __launch_bounds__(256) void ln_attn_kernel(
    const f16* __restrict__ h2, const float* __restrict__ lnw,
    const float* __restrict__ lnb, const float* __restrict__ aw,
    f16* __restrict__ att_out) {
  const int b = blockIdx.x, tid = threadIdx.x;
  const int lane = tid & 63, wave = tid >> 6;
  __shared__ float smu[512], sis[512], ssc[512];
  __shared__ float vbuf[256];
  __shared__ float red[16];

  float vj = aw[tid] * lnw[tid];
  float uj = aw[tid] * lnb[tid];
  vbuf[tid] = vj;
  float rv = vj, ru = uj;
#pragma unroll
  for (int m = 1; m < 64; m <<= 1) { rv += __shfl_xor(rv, m, 64); ru += __shfl_xor(ru, m, 64); }
  if (lane == 0) { red[wave] = rv; red[4 + wave] = ru; }
  __syncthreads();
  const float Vsum = red[0] + red[1] + red[2] + red[3];
  const float Csum = red[4] + red[5] + red[6] + red[7];
  const f32x4 v4 = *(const f32x4*)&vbuf[lane * 4];
  const f16* hb = h2 + (size_t)b * 512 * 256;

  for (int tt = wave; tt < 512; tt += 4) {
    f16x4 hv = *(const f16x4*)(hb + (size_t)tt * 256 + lane * 4);
    float h0 = (float)hv[0], h1 = (float)hv[1], h2v = (float)hv[2], h3 = (float)hv[3];
    float s1 = h0 + h1 + h2v + h3;
    float s2 = h0 * h0 + h1 * h1 + h2v * h2v + h3 * h3;
    float sv = h0 * v4[0] + h1 * v4[1] + h2v * v4[2] + h3 * v4[3];
#pragma unroll
    for (int m = 1; m < 64; m <<= 1) {
      s1 += __shfl_xor(s1, m, 64);
      s2 += __shfl_xor(s2, m, 64);
      sv += __shfl_xor(sv, m, 64);
    }
    if (lane == 0) {
      float mu = s1 * (1.0f / 256.0f);
      float var = s2 * (1.0f / 256.0f) - mu * mu;
      float is = rsqrtf(var + 1e-5f);
      smu[tt] = mu; sis[tt] = is;
      ssc[tt] = (sv - mu * Vsum) * is + Csum;
    }
  }
  __syncthreads();
  // softmax over 512 scores
  float a0 = ssc[tid], a1 = ssc[tid + 256];
  float mx = fmaxf(a0, a1);
#pragma unroll
  for (int m = 1; m < 64; m <<= 1) mx = fmaxf(mx, __shfl_xor(mx, m, 64));
  if (lane == 0) red[wave] = mx;
  __syncthreads();
  mx = fmaxf(fmaxf(red[0], red[1]), fmaxf(red[2], red[3]));
  __syncthreads();  // protect red reuse
  float p0 = exp2f((a0 - mx) * 1.44269504f);
  float p1 = exp2f((a1 - mx) * 1.44269504f);
  float ps = p0 + p1;
  float pm = p0 * smu[tid] * sis[tid] + p1 * smu[tid + 256] * sis[tid + 256];
#pragma unroll
  for (int m = 1; m < 64; m <<= 1) { ps += __shfl_xor(ps, m, 64); pm += __shfl_xor(pm, m, 64); }
  if (lane == 0) { red[wave] = ps; red[8 + wave] = pm; }
  __syncthreads();
  const float S = red[0] + red[1] + red[2] + red[3];
  const float PM = (red[8] + red[9] + red[10] + red[11]) / S;
  ssc[tid] = p0 / S * sis[tid];          // alpha_t
  ssc[tid + 256] = p1 / S * sis[tid + 256];
  __syncthreads();
  // pass 2: attended_j = lnw_j*(sum_t alpha_t h_tj - PM) + lnb_j
  float acc = 0.f;
  for (int t = 0; t < 512; ++t) acc += ssc[t] * (float)hb[(size_t)t * 256 + tid];
  float att = lnw[tid] * (acc - PM) + lnb[tid];
  att_out[b * 256 + tid] = (f16)att;
}

// ---------------- launch ----------------

extern "C" void kernel_launch(void* const* d_in, const int* in_sizes, int n_in,
                              void* d_out, int out_size, void* d_ws, size_t ws_size,
                              hipStream_t stream) {
  (void)in_sizes; (void)n_in; (void)out_size; (void)ws_size;
  const float* x    = (const float*)d_in[0];
  const float* wih0 = (const float*)d_in[1];
  const float* whh0 = (const float*)d_in[2];
  const float* bih0 = (const float*)d_in[3];
  const float* bhh0 = (const float*)d_in[4];
  const float* wih1 = (const float*)d_in[5];
  const float* whh1 = (const float*)d_in[6];
  const float* bih1 = (const float*)d_in[7];
  const float* bhh1 = (const float*)d_in[8];
  const float* lnw  = (const float*)d_in[9];
  const float* lnb  = (const float*)d_in[10];
  const float* aw   = (const float*)d_in[11];
  const float* fcw  = (const float*)d_in[12];
  const float* fcb  = (const float*)d_in[13];

  char* ws = (char*)d_ws;
  f16* x_h      = (f16*)(ws + 0);            // 50331648 B; region reused after GEMM0:
  f16* h1       = (f16*)(ws + 0);            //   h1: 16777216 B
  f16* h2       = (f16*)(ws + 16777216);     //   h2: 16777216 B
  f16* wih0_h   = (f16*)(ws + 50331648);     // 1572864
  f16* wih1_h   = (f16*)(ws + 51904512);     // 524288
  f16* fcw_h    = (f16*)(ws + 52428800);     // 15627264
  uint32_t* wq0 = (uint32_t*)(ws + 68056064);// 262144
  uint32_t* wq1 = (uint32_t*)(ws + 68318208);// 262144
  float* qmul0  = (float*)(ws + 68580352);   // 4096
  float* dmul0  = (float*)(ws + 68584448);   // 4096
  float* qmul1  = (float*)(ws + 68588544);   // 4096
  float* dmul1  = (float*)(ws + 68592640);   // 4096
  float* bsum0  = (float*)(ws + 69104640);   // 4096
  float* bsum1  = (float*)(ws + 69108736);   // 4096
  f16* att_h    = (f16*)(ws + 69112832);     // 32768
  f16* xg       = (f16*)(ws + 69145600);     // 67108864 (shared by both layers)

  convert_all_kernel<<<4096, 256, 0, stream>>>(x, x_h, wih0, wih0_h, wih1, wih1_h, fcw, fcw_h);
  addvec2_kernel<<<8, 256, 0, stream>>>(bih0, bhh0, bsum0, bih1, bhh1, bsum1);
  rowscale2_kernel<<<32, 256, 0, stream>>>(whh0, qmul0, dmul0, whh1, qmul1, dmul1);
  wq82_kernel<<<512, 256, 0, stream>>>(whh0, qmul0, wq0, whh1, qmul1, wq1);

  // layer 0: xg0 = x @ w_ih0^T + (b_ih0 + b_hh0)
  gemm_bt_kernel<0><<<dim3(8, 256), 256, 0, stream>>>(x_h, wih0_h, bsum0, xg, 32768, 1024, 768);
  lstm_rec_kernel<<<64, 512, 0, stream>>>(xg, (const u32x4*)wq0, dmul0, h1, 512);
  // layer 1
  gemm_bt_kernel<0><<<dim3(8, 256), 256, 0, stream>>>(h1, wih1_h, bsum1, xg, 32768, 1024, 256);
  lstm_rec_kernel<<<64, 512, 0, stream>>>(xg, (const u32x4*)wq1, dmul1, h2, 512);
  // LN + attention pooling
  ln_attn_kernel<<<64, 256, 0, stream>>>(h2, lnw, lnb, aw, att_h);
  // FC: out = attended @ fc_w^T + fc_b  (fp32 out)
  gemm_bt_kernel<1><<<dim3(239, 1), 256, 0, stream>>>(att_h, fcw_h, fcb, d_out, 64, 30522, 256);
}

// Round 15
// 1146.483 us; speedup vs baseline: 2.6073x; 1.3818x over previous
//
#include <hip/hip_runtime.h>
#include <cstdint>

typedef _Float16 f16;
using f16x2 = __attribute__((ext_vector_type(2))) _Float16;
using f16x4 = __attribute__((ext_vector_type(4))) _Float16;
using f16x8 = __attribute__((ext_vector_type(8))) _Float16;
using f32x4 = __attribute__((ext_vector_type(4))) float;
using u32x4 = __attribute__((ext_vector_type(4))) uint32_t;
using i32x4 = __attribute__((ext_vector_type(4))) int;

#define GLB_PTR(p) ((const __attribute__((address_space(1))) void*)(p))
#define LDS_PTR(p) ((__attribute__((address_space(3))) void*)(p))

// Newton-refined reciprocal: <=1 ulp at rcp + 2 fma (proven R9).
__device__ __forceinline__ float rcp_nr(float x) {
  float r = __builtin_amdgcn_rcpf(x);
  return fmaf(fmaf(-x, r, 1.0f), r, r);
}
__device__ __forceinline__ float sigmoidf_(float x) {
  float e = exp2f(-x * 1.44269504088896f);
  return rcp_nr(1.0f + e);
}
__device__ __forceinline__ float tanhf_(float x) {
  float e = exp2f(x * 2.88539008177793f);   // exp(2x)
  return 1.0f - 2.0f * rcp_nr(e + 1.0f);
}

// i8 MFMA. B (weights) pinned in AGPR; accumulator in VGPR (proven R14).
__device__ __forceinline__ void mfma_i8(i32x4& d, u32x4 a, u32x4 b) {
  asm("v_mfma_i32_16x16x64_i8 %0, %1, %2, %0"
      : "+v"(d)
      : "v"(a), "a"(b));
}
__device__ __forceinline__ void mfma_i8_z(i32x4& d, u32x4 a, u32x4 b, const i32x4& zc) {
  asm("v_mfma_i32_16x16x64_i8 %0, %1, %2, %3"
      : "=v"(d)
      : "v"(a), "a"(b), "v"(zc));
}

// ---------------- fused prep kernels (proven R14) ----------------

__global__ void convert_all_kernel(const float* __restrict__ x, f16* __restrict__ x_h,
                                   const float* __restrict__ w0, f16* __restrict__ w0_h,
                                   const float* __restrict__ w1, f16* __restrict__ w1_h,
                                   const float* __restrict__ fw, f16* __restrict__ fw_h) {
  const long N0 = 6291456, N1 = N0 + 196608, N2 = N1 + 65536, N3 = N2 + 1953408;
  long stride = (long)gridDim.x * blockDim.x;
  for (long i = blockIdx.x * (long)blockDim.x + threadIdx.x; i < N3; i += stride) {
    const float* in; f16* out; long j;
    if (i < N0)      { in = x;  out = x_h;  j = i; }
    else if (i < N1) { in = w0; out = w0_h; j = i - N0; }
    else if (i < N2) { in = w1; out = w1_h; j = i - N1; }
    else             { in = fw; out = fw_h; j = i - N2; }
    f32x4 v = *(const f32x4*)(in + j * 4);
    f16x4 h;
    h[0] = (f16)v[0]; h[1] = (f16)v[1]; h[2] = (f16)v[2]; h[3] = (f16)v[3];
    *(f16x4*)(out + j * 4) = h;
  }
}

__global__ void addvec2_kernel(const float* __restrict__ a0, const float* __restrict__ b0,
                               float* __restrict__ o0,
                               const float* __restrict__ a1, const float* __restrict__ b1,
                               float* __restrict__ o1) {
  int i = blockIdx.x * blockDim.x + threadIdx.x;  // 2048 threads
  if (i < 1024) o0[i] = a0[i] + b0[i];
  else if (i < 2048) o1[i - 1024] = a1[i - 1024] + b1[i - 1024];
}

__global__ __launch_bounds__(256) void rowscale2_kernel(
    const float* __restrict__ whh0, float* __restrict__ qmul0, float* __restrict__ dmul0,
    const float* __restrict__ whh1, float* __restrict__ qmul1, float* __restrict__ dmul1) {
  int blk = blockIdx.x;  // 32 blocks: 0-15 -> whh0, 16-31 -> whh1
  const float* whh; float* qmul; float* dmul;
  if (blk < 16) { whh = whh0; qmul = qmul0; dmul = dmul0; }
  else          { whh = whh1; qmul = qmul1; dmul = dmul1; blk -= 16; }
  const int wv = (blk * 256 + (int)threadIdx.x) >> 6;  // wave 0..63
  const int lane = threadIdx.x & 63;
  for (int rr = 0; rr < 16; ++rr) {
    int r = wv * 16 + rr;
    f32x4 v = *(const f32x4*)(whh + r * 256 + lane * 4);
    float m = fmaxf(fmaxf(fabsf(v[0]), fabsf(v[1])), fmaxf(fabsf(v[2]), fabsf(v[3])));
#pragma unroll
    for (int s = 1; s < 64; s <<= 1) m = fmaxf(m, __shfl_xor(m, s, 64));
    if (lane == 0) {
      float sr = fmaxf(m, 1e-8f);
      qmul[r] = 127.0f / sr;
      dmul[r] = sr / 16129.0f;
    }
  }
}

// int8 B-fragment prep (R7-proven k-map).
__global__ void wq82_kernel(const float* __restrict__ whh0, const float* __restrict__ qmul0,
                            uint32_t* __restrict__ wq0,
                            const float* __restrict__ whh1, const float* __restrict__ qmul1,
                            uint32_t* __restrict__ wq1) {
  int i = blockIdx.x * blockDim.x + threadIdx.x;  // 131072 threads
  const float* whh; const float* qmul; uint32_t* wq;
  if (i < 65536) { whh = whh0; qmul = qmul0; wq = wq0; }
  else           { whh = whh1; qmul = qmul1; wq = wq1; i -= 65536; }
  int d = i & 3, l = (i >> 2) & 63, c = (i >> 8) & 3, t = i >> 10;
  int r = t * 16 + (l & 15);
  int k0 = c * 64 + ((l >> 4) & 3) * 16 + d * 4;
  float qm = qmul[r];
  uint32_t out = 0;
#pragma unroll
  for (int e = 0; e < 4; ++e) {
    int q = __float2int_rn(whh[r * 256 + k0 + e] * qm);
    q = min(127, max(-127, q));
    out |= ((uint32_t)(uint8_t)(int8_t)q) << (8 * e);
  }
  wq[i] = out;
}

// ---------------- GEMM: C[m,n] = sum_k A[m,k]*B[n,k] + bias[n] ----------------
// Staging via global_load_lds width=16 (R13-proven).

template <int OUTF32>
__global__ __launch_bounds__(256) void gemm_bt_kernel(
    const f16* __restrict__ A, const f16* __restrict__ B,
    const float* __restrict__ bias, void* __restrict__ Cout,
    int M, int N, int K) {
  __shared__ __align__(16) f16 Al[128 * 32];
  __shared__ __align__(16) f16 Bl[128 * 32];
  const int tid = threadIdx.x;
  const int lane = tid & 63, wave = tid >> 6;
  const int bn = blockIdx.x, bm = blockIdx.y;
  const int qm = (wave >> 1) * 64, qn = (wave & 1) * 64;

  f32x4 acc[4][4];
#pragma unroll
  for (int i = 0; i < 4; ++i)
#pragma unroll
    for (int j = 0; j < 4; ++j) acc[i][j] = (f32x4){0.f, 0.f, 0.f, 0.f};

  const int c0 = tid, c1 = 256 + tid;
  const int row0 = c0 >> 2, off0 = c0 & 3;
  const int row1 = c1 >> 2, off1 = c1 & 3;
  const int gmA0 = min(bm * 128 + row0, M - 1);
  const int gmA1 = min(bm * 128 + row1, M - 1);
  const int gnB0 = min(bn * 128 + row0, N - 1);
  const int gnB1 = min(bn * 128 + row1, N - 1);

  // wave-uniform LDS bases; HW writes base + lane*16
  f16* ldsA0 = &Al[(wave * 64) * 8];
  f16* ldsA1 = &Al[(256 + wave * 64) * 8];
  f16* ldsB0 = &Bl[(wave * 64) * 8];
  f16* ldsB1 = &Bl[(256 + wave * 64) * 8];

  for (int k0 = 0; k0 < K; k0 += 32) {
    __syncthreads();  // previous iteration's LDS frag reads done
    __builtin_amdgcn_global_load_lds(GLB_PTR(A + (size_t)gmA0 * K + k0 + off0 * 8),
                                     LDS_PTR(ldsA0), 16, 0, 0);
    __builtin_amdgcn_global_load_lds(GLB_PTR(A + (size_t)gmA1 * K + k0 + off1 * 8),
                                     LDS_PTR(ldsA1), 16, 0, 0);
    __builtin_amdgcn_global_load_lds(GLB_PTR(B + (size_t)gnB0 * K + k0 + off0 * 8),
                                     LDS_PTR(ldsB0), 16, 0, 0);
    __builtin_amdgcn_global_load_lds(GLB_PTR(B + (size_t)gnB1 * K + k0 + off1 * 8),
                                     LDS_PTR(ldsB1), 16, 0, 0);
    asm volatile("s_waitcnt vmcnt(0)" ::: "memory");
    __syncthreads();
    f16x8 af[4], bf[4];
#pragma unroll
    for (int mt = 0; mt < 4; ++mt)
      af[mt] = *(const f16x8*)&Al[(qm + mt * 16 + (lane & 15)) * 32 + (lane >> 4) * 8];
#pragma unroll
    for (int nt = 0; nt < 4; ++nt)
      bf[nt] = *(const f16x8*)&Bl[(qn + nt * 16 + (lane & 15)) * 32 + (lane >> 4) * 8];
#pragma unroll
    for (int mt = 0; mt < 4; ++mt)
#pragma unroll
      for (int nt = 0; nt < 4; ++nt)
        acc[mt][nt] = __builtin_amdgcn_mfma_f32_16x16x32_f16(af[mt], bf[nt], acc[mt][nt], 0, 0, 0);
  }

#pragma unroll
  for (int mt = 0; mt < 4; ++mt)
#pragma unroll
    for (int nt = 0; nt < 4; ++nt)
#pragma unroll
      for (int j = 0; j < 4; ++j) {
        int gm = bm * 128 + qm + mt * 16 + (lane >> 4) * 4 + j;
        int gn = bn * 128 + qn + nt * 16 + (lane & 15);
        if (gm < M && gn < N) {
          float v = acc[mt][nt][j] + bias[gn];
          if (OUTF32)
            ((float*)Cout)[(size_t)gm * N + gn] = v;
          else
            ((f16*)Cout)[(size_t)gm * N + gn] = (f16)v;
        }
      }
}

// ---------------- persistent LSTM recurrence (int8 MFMA, two-level h) ----------------
// R14-proven geometry (649 us/layer, absmax 0.0078): 64 blocks x 512 threads (8 waves),
// 8 weight tiles/wave in AGPR, VGPR accumulators, zero-C first chunk, two-level h.
// R15 delta — kg-split activation (numerics-identical redistribution):
//   asel = ((l15&3)==1) puts h_lo in A rows 1,5,9,13 (rows 4i = h_hi) -> EVERY kg
//   group's D reg0/reg1 = (hi, lo) exact duplicates (integer MFMA). So:
//   kg 0,1 lanes process only the uA cell; kg 2,3 only uB (acc 2j+sel, scale/xg at
//   u + 256*j == R9's base+128*(2j+sel) mapping). Per-lane act work halves.
//   Writes: kg==0 -> uA bytes, kg==2 -> uB bytes (each byte exactly once).

__global__ __launch_bounds__(512, 2) void lstm_rec_kernel(
    const f16* __restrict__ xg,          // [B*T, 1024], biases included
    const u32x4* __restrict__ wq,        // [64 t][4 c][64 l] u32x4 int8 frags
    const float* __restrict__ dmul,      // [1024] per-row dequant scale
    f16* __restrict__ h_out,             // [B*T, 256]
    int T) {
  __shared__ __align__(16) uint8_t h8[2][512];   // [hi 256 | lo 256], double-buffered
  const int b = blockIdx.x;
  const int tid = threadIdx.x;
  const int w = tid >> 6, lane = tid & 63;
  const int l15 = lane & 15, kg = (lane >> 4) & 3;
  const int base = w * 16 + l15;
  const int asel = ((l15 & 3) == 1) ? 256 : 0;  // rows 1,5,9,13 read lo slice
  const int sel = kg >> 1;                       // 0: this lane handles uA; 1: uB
  const int u = base + sel * 128;                // unit this lane processes

  // all 8 tiles -> AGPR (used only via "a" asm operands)
  u32x4 wt[8][4];
#pragma unroll
  for (int j = 0; j < 8; ++j)
#pragma unroll
    for (int c = 0; c < 4; ++c)
      wt[j][c] = wq[((w + 8 * j) * 4 + c) * 64 + lane];
  // scales for this lane's cell only: gate j of unit u -> dmul[u + 256*j]
  float sc[4], sc2[4];
#pragma unroll
  for (int j = 0; j < 4; ++j) {
    sc[j] = dmul[u + 256 * j];
    sc2[j] = sc[j] * (1.0f / 127.0f);
  }

  if (tid < 256) ((uint32_t*)h8)[tid] = 0;   // zero both buffers (1 KB)
  float cst = 0.f;
  __syncthreads();

  const f16* xt = xg + (size_t)b * T * 1024;
  f16* hob = h_out + (size_t)b * T * 256;

  // prologue: prefetch step-0 xg contributions (this lane's cell only)
  f16 xc[4];
#pragma unroll
  for (int j = 0; j < 4; ++j) xc[j] = xt[u + 256 * j];

  const i32x4 zc = (i32x4){0, 0, 0, 0};

  for (int t = 0; t < T; ++t) {
    // consume prefetched xg; issue next step's loads (hidden under this step)
    float xv[4];
#pragma unroll
    for (int j = 0; j < 4; ++j) xv[j] = (float)xc[j];
    const f16* xn = (t + 1 < T) ? xt + 1024 : xt;
#pragma unroll
    for (int j = 0; j < 4; ++j) xc[j] = xn[u + 256 * j];

    const uint8_t* hq = h8[t & 1] + asel;
    u32x4 afr0 = *(const u32x4*)(hq + 0 * 64 + kg * 16);
    i32x4 a0, a1, a2, a3, a4, a5, a6, a7;
    mfma_i8_z(a0, afr0, wt[0][0], zc);
    mfma_i8_z(a1, afr0, wt[1][0], zc);
    mfma_i8_z(a2, afr0, wt[2][0], zc);
    mfma_i8_z(a3, afr0, wt[3][0], zc);
    mfma_i8_z(a4, afr0, wt[4][0], zc);
    mfma_i8_z(a5, afr0, wt[5][0], zc);
    mfma_i8_z(a6, afr0, wt[6][0], zc);
    mfma_i8_z(a7, afr0, wt[7][0], zc);
#pragma unroll
    for (int c = 1; c < 4; ++c) {
      u32x4 afr = *(const u32x4*)(hq + c * 64 + kg * 16);
      mfma_i8(a0, afr, wt[0][c]);
      mfma_i8(a1, afr, wt[1][c]);
      mfma_i8(a2, afr, wt[2][c]);
      mfma_i8(a3, afr, wt[3][c]);
      mfma_i8(a4, afr, wt[4][c]);
      mfma_i8(a5, afr, wt[5][c]);
      mfma_i8(a6, afr, wt[6][c]);
      mfma_i8(a7, afr, wt[7][c]);
    }
    // this lane's cell: gate j -> acc tile 2j+sel; reg0 = hi, reg1 = lo (all kg valid)
    float dI0 = sel ? (float)a1[0] : (float)a0[0];
    float dI1 = sel ? (float)a1[1] : (float)a0[1];
    float dF0 = sel ? (float)a3[0] : (float)a2[0];
    float dF1 = sel ? (float)a3[1] : (float)a2[1];
    float dG0 = sel ? (float)a5[0] : (float)a4[0];
    float dG1 = sel ? (float)a5[1] : (float)a4[1];
    float dO0 = sel ? (float)a7[0] : (float)a6[0];
    float dO1 = sel ? (float)a7[1] : (float)a6[1];
    float gI = dI0 * sc[0] + dI1 * sc2[0] + xv[0];
    float gF = dF0 * sc[1] + dF1 * sc2[1] + xv[1];
    float gG = dG0 * sc[2] + dG1 * sc2[2] + xv[2];
    float gO = dO0 * sc[3] + dO1 * sc2[3] + xv[3];
    float iv = sigmoidf_(gI), fv = sigmoidf_(gF);
    float gv = tanhf_(gG),   ov = sigmoidf_(gO);
    cst = fv * cst + iv * gv;
    float hv = ov * tanhf_(cst);
    int hi = __float2int_rn(hv * 127.0f);
    int lo = __float2int_rn(fmaf((float)hi, -127.0f, hv * 16129.0f));
    uint8_t* hn = (uint8_t*)h8[(t + 1) & 1];
    if ((kg & 1) == 0) {   // kg==0 writes uA, kg==2 writes uB — each byte once
      hn[u] = (uint8_t)(int8_t)hi;
      hn[256 + u] = (uint8_t)(int8_t)lo;
      hob[(size_t)t * 256 + u] = (f16)hv;   // global h (vmcnt floats, never drained)
    }
    xt += 1024;
    asm volatile("s_waitcnt lgkmcnt(0)" ::: "memory");  // h8 writes visible
    __builtin_amdgcn_s_barrier();
    __builtin_amdgcn_sched_barrier(0);
  }
}

// ---------------- fused LayerNorm + attention pooling ----------------
// one block per batch, 256 threads.

__global__ __launch_bounds__(256) void ln_attn_kernel(
    const f16* __restrict__ h2, const float* __restrict__ lnw,
    const float* __restrict__ lnb, const float* __restrict__ aw,
    f16* __restrict__ att_out) {
  const int b = blockIdx.x, tid = threadIdx.x;
  const int lane = tid & 63, wave = tid >> 6;
  __shared__ float smu[512], sis[512], ssc[512];
  __shared__ float vbuf[256];
  __shared__ float red[16];

  float vj = aw[tid] * lnw[tid];
  float uj = aw[tid] * lnb[tid];
  vbuf[tid] = vj;
  float rv = vj, ru = uj;
#pragma unroll
  for (int m = 1; m < 64; m <<= 1) { rv += __shfl_xor(rv, m, 64); ru += __shfl_xor(ru, m, 64); }
  if (lane == 0) { red[wave] = rv; red[4 + wave] = ru; }
  __syncthreads();
  const float Vsum = red[0] + red[1] + red[2] + red[3];
  const float Csum = red[4] + red[5] + red[6] + red[7];
  const f32x4 v4 = *(const f32x4*)&vbuf[lane * 4];
  const f16* hb = h2 + (size_t)b * 512 * 256;

  for (int tt = wave; tt < 512; tt += 4) {
    f16x4 hv = *(const f16x4*)(hb + (size_t)tt * 256 + lane * 4);
    float h0 = (float)hv[0], h1 = (float)hv[1], h2v = (float)hv[2], h3 = (float)hv[3];
    float s1 = h0 + h1 + h2v + h3;
    float s2 = h0 * h0 + h1 * h1 + h2v * h2v + h3 * h3;
    float sv = h0 * v4[0] + h1 * v4[1] + h2v * v4[2] + h3 * v4[3];
#pragma unroll
    for (int m = 1; m < 64; m <<= 1) {
      s1 += __shfl_xor(s1, m, 64);
      s2 += __shfl_xor(s2, m, 64);
      sv += __shfl_xor(sv, m, 64);
    }
    if (lane == 0) {
      float mu = s1 * (1.0f / 256.0f);
      float var = s2 * (1.0f / 256.0f) - mu * mu;
      float is = rsqrtf(var + 1e-5f);
      smu[tt] = mu; sis[tt] = is;
      ssc[tt] = (sv - mu * Vsum) * is + Csum;
    }
  }
  __syncthreads();
  // softmax over 512 scores
  float a0 = ssc[tid], a1 = ssc[tid + 256];
  float mx = fmaxf(a0, a1);
#pragma unroll
  for (int m = 1; m < 64; m <<= 1) mx = fmaxf(mx, __shfl_xor(mx, m, 64));
  if (lane == 0) red[wave] = mx;
  __syncthreads();
  mx = fmaxf(fmaxf(red[0], red[1]), fmaxf(red[2], red[3]));
  __syncthreads();  // protect red reuse
  float p0 = exp2f((a0 - mx) * 1.44269504f);
  float p1 = exp2f((a1 - mx) * 1.44269504f);
  float ps = p0 + p1;
  float pm = p0 * smu[tid] * sis[tid] + p1 * smu[tid + 256] * sis[tid + 256];
#pragma unroll
  for (int m = 1; m < 64; m <<= 1) { ps += __shfl_xor(ps, m, 64); pm += __shfl_xor(pm, m, 64); }
  if (lane == 0) { red[wave] = ps; red[8 + wave] = pm; }
  __syncthreads();
  const float S = red[0] + red[1] + red[2] + red[3];
  const float PM = (red[8] + red[9] + red[10] + red[11]) / S;
  ssc[tid] = p0 / S * sis[tid];          // alpha_t
  ssc[tid + 256] = p1 / S * sis[tid + 256];
  __syncthreads();
  // pass 2: attended_j = lnw_j*(sum_t alpha_t h_tj - PM) + lnb_j
  float acc = 0.f;
  for (int t = 0; t < 512; ++t) acc += ssc[t] * (float)hb[(size_t)t * 256 + tid];
  float att = lnw[tid] * (acc - PM) + lnb[tid];
  att_out[b * 256 + tid] = (f16)att;
}

// ---------------- launch ----------------

extern "C" void kernel_launch(void* const* d_in, const int* in_sizes, int n_in,
                              void* d_out, int out_size, void* d_ws, size_t ws_size,
                              hipStream_t stream) {
  (void)in_sizes; (void)n_in; (void)out_size; (void)ws_size;
  const float* x    = (const float*)d_in[0];
  const float* wih0 = (const float*)d_in[1];
  const float* whh0 = (const float*)d_in[2];
  const float* bih0 = (const float*)d_in[3];
  const float* bhh0 = (const float*)d_in[4];
  const float* wih1 = (const float*)d_in[5];
  const float* whh1 = (const float*)d_in[6];
  const float* bih1 = (const float*)d_in[7];
  const float* bhh1 = (const float*)d_in[8];
  const float* lnw  = (const float*)d_in[9];
  const float* lnb  = (const float*)d_in[10];
  const float* aw   = (const float*)d_in[11];
  const float* fcw  = (const float*)d_in[12];
  const float* fcb  = (const float*)d_in[13];

  char* ws = (char*)d_ws;
  f16* x_h      = (f16*)(ws + 0);            // 50331648 B; region reused after GEMM0:
  f16* h1       = (f16*)(ws + 0);            //   h1: 16777216 B
  f16* h2       = (f16*)(ws + 16777216);     //   h2: 16777216 B
  f16* wih0_h   = (f16*)(ws + 50331648);     // 1572864
  f16* wih1_h   = (f16*)(ws + 51904512);     // 524288
  f16* fcw_h    = (f16*)(ws + 52428800);     // 15627264
  uint32_t* wq0 = (uint32_t*)(ws + 68056064);// 262144
  uint32_t* wq1 = (uint32_t*)(ws + 68318208);// 262144
  float* qmul0  = (float*)(ws + 68580352);   // 4096
  float* dmul0  = (float*)(ws + 68584448);   // 4096
  float* qmul1  = (float*)(ws + 68588544);   // 4096
  float* dmul1  = (float*)(ws + 68592640);   // 4096
  float* bsum0  = (float*)(ws + 69104640);   // 4096
  float* bsum1  = (float*)(ws + 69108736);   // 4096
  f16* att_h    = (f16*)(ws + 69112832);     // 32768
  f16* xg       = (f16*)(ws + 69145600);     // 67108864 (shared by both layers)

  convert_all_kernel<<<4096, 256, 0, stream>>>(x, x_h, wih0, wih0_h, wih1, wih1_h, fcw, fcw_h);
  addvec2_kernel<<<8, 256, 0, stream>>>(bih0, bhh0, bsum0, bih1, bhh1, bsum1);
  rowscale2_kernel<<<32, 256, 0, stream>>>(whh0, qmul0, dmul0, whh1, qmul1, dmul1);
  wq82_kernel<<<512, 256, 0, stream>>>(whh0, qmul0, wq0, whh1, qmul1, wq1);

  // layer 0: xg0 = x @ w_ih0^T + (b_ih0 + b_hh0)
  gemm_bt_kernel<0><<<dim3(8, 256), 256, 0, stream>>>(x_h, wih0_h, bsum0, xg, 32768, 1024, 768);
  lstm_rec_kernel<<<64, 512, 0, stream>>>(xg, (const u32x4*)wq0, dmul0, h1, 512);
  // layer 1
  gemm_bt_kernel<0><<<dim3(8, 256), 256, 0, stream>>>(h1, wih1_h, bsum1, xg, 32768, 1024, 256);
  lstm_rec_kernel<<<64, 512, 0, stream>>>(xg, (const u32x4*)wq1, dmul1, h2, 512);
  // LN + attention pooling
  ln_attn_kernel<<<64, 256, 0, stream>>>(h2, lnw, lnb, aw, att_h);
  // FC: out = attended @ fc_w^T + fc_b  (fp32 out)
  gemm_bt_kernel<1><<<dim3(239, 1), 256, 0, stream>>>(att_h, fcw_h, fcb, d_out, 64, 30522, 256);
}

// Round 16
// 1122.657 us; speedup vs baseline: 2.6626x; 1.0212x over previous
//
#include <hip/hip_runtime.h>
#include <cstdint>

typedef _Float16 f16;
using f16x2 = __attribute__((ext_vector_type(2))) _Float16;
using f16x4 = __attribute__((ext_vector_type(4))) _Float16;
using f16x8 = __attribute__((ext_vector_type(8))) _Float16;
using f32x4 = __attribute__((ext_vector_type(4))) float;
using u32x4 = __attribute__((ext_vector_type(4))) uint32_t;
using i32x4 = __attribute__((ext_vector_type(4))) int;

#define GLB_PTR(p) ((const __attribute__((address_space(1))) void*)(p))
#define LDS_PTR(p) ((__attribute__((address_space(3))) void*)(p))

// Newton-refined reciprocal: <=1 ulp at rcp + 2 fma (proven R9).
__device__ __forceinline__ float rcp_nr(float x) {
  float r = __builtin_amdgcn_rcpf(x);
  return fmaf(fmaf(-x, r, 1.0f), r, r);
}
__device__ __forceinline__ float sigmoidf_(float x) {
  float e = exp2f(-x * 1.44269504088896f);
  return rcp_nr(1.0f + e);
}
__device__ __forceinline__ float tanhf_(float x) {
  float e = exp2f(x * 2.88539008177793f);   // exp(2x)
  return 1.0f - 2.0f * rcp_nr(e + 1.0f);
}

// i8 MFMA. B (weights) pinned in AGPR; accumulator in VGPR (proven R14).
__device__ __forceinline__ void mfma_i8(i32x4& d, u32x4 a, u32x4 b) {
  asm("v_mfma_i32_16x16x64_i8 %0, %1, %2, %0"
      : "+v"(d)
      : "v"(a), "a"(b));
}
__device__ __forceinline__ void mfma_i8_z(i32x4& d, u32x4 a, u32x4 b, const i32x4& zc) {
  asm("v_mfma_i32_16x16x64_i8 %0, %1, %2, %3"
      : "=v"(d)
      : "v"(a), "a"(b), "v"(zc));
}

// ---------------- fused prep kernels (proven R14) ----------------

__global__ void convert_all_kernel(const float* __restrict__ x, f16* __restrict__ x_h,
                                   const float* __restrict__ w0, f16* __restrict__ w0_h,
                                   const float* __restrict__ w1, f16* __restrict__ w1_h,
                                   const float* __restrict__ fw, f16* __restrict__ fw_h) {
  const long N0 = 6291456, N1 = N0 + 196608, N2 = N1 + 65536, N3 = N2 + 1953408;
  long stride = (long)gridDim.x * blockDim.x;
  for (long i = blockIdx.x * (long)blockDim.x + threadIdx.x; i < N3; i += stride) {
    const float* in; f16* out; long j;
    if (i < N0)      { in = x;  out = x_h;  j = i; }
    else if (i < N1) { in = w0; out = w0_h; j = i - N0; }
    else if (i < N2) { in = w1; out = w1_h; j = i - N1; }
    else             { in = fw; out = fw_h; j = i - N2; }
    f32x4 v = *(const f32x4*)(in + j * 4);
    f16x4 h;
    h[0] = (f16)v[0]; h[1] = (f16)v[1]; h[2] = (f16)v[2]; h[3] = (f16)v[3];
    *(f16x4*)(out + j * 4) = h;
  }
}

__global__ void addvec2_kernel(const float* __restrict__ a0, const float* __restrict__ b0,
                               float* __restrict__ o0,
                               const float* __restrict__ a1, const float* __restrict__ b1,
                               float* __restrict__ o1) {
  int i = blockIdx.x * blockDim.x + threadIdx.x;  // 2048 threads
  if (i < 1024) o0[i] = a0[i] + b0[i];
  else if (i < 2048) o1[i - 1024] = a1[i - 1024] + b1[i - 1024];
}

__global__ __launch_bounds__(256) void rowscale2_kernel(
    const float* __restrict__ whh0, float* __restrict__ qmul0, float* __restrict__ dmul0,
    const float* __restrict__ whh1, float* __restrict__ qmul1, float* __restrict__ dmul1) {
  int blk = blockIdx.x;  // 32 blocks: 0-15 -> whh0, 16-31 -> whh1
  const float* whh; float* qmul; float* dmul;
  if (blk < 16) { whh = whh0; qmul = qmul0; dmul = dmul0; }
  else          { whh = whh1; qmul = qmul1; dmul = dmul1; blk -= 16; }
  const int wv = (blk * 256 + (int)threadIdx.x) >> 6;  // wave 0..63
  const int lane = threadIdx.x & 63;
  for (int rr = 0; rr < 16; ++rr) {
    int r = wv * 16 + rr;
    f32x4 v = *(const f32x4*)(whh + r * 256 + lane * 4);
    float m = fmaxf(fmaxf(fabsf(v[0]), fabsf(v[1])), fmaxf(fabsf(v[2]), fabsf(v[3])));
#pragma unroll
    for (int s = 1; s < 64; s <<= 1) m = fmaxf(m, __shfl_xor(m, s, 64));
    if (lane == 0) {
      float sr = fmaxf(m, 1e-8f);
      qmul[r] = 127.0f / sr;
      dmul[r] = sr / 16129.0f;
    }
  }
}

// int8 B-fragment prep (R7-proven k-map).
__global__ void wq82_kernel(const float* __restrict__ whh0, const float* __restrict__ qmul0,
                            uint32_t* __restrict__ wq0,
                            const float* __restrict__ whh1, const float* __restrict__ qmul1,
                            uint32_t* __restrict__ wq1) {
  int i = blockIdx.x * blockDim.x + threadIdx.x;  // 131072 threads
  const float* whh; const float* qmul; uint32_t* wq;
  if (i < 65536) { whh = whh0; qmul = qmul0; wq = wq0; }
  else           { whh = whh1; qmul = qmul1; wq = wq1; i -= 65536; }
  int d = i & 3, l = (i >> 2) & 63, c = (i >> 8) & 3, t = i >> 10;
  int r = t * 16 + (l & 15);
  int k0 = c * 64 + ((l >> 4) & 3) * 16 + d * 4;
  float qm = qmul[r];
  uint32_t out = 0;
#pragma unroll
  for (int e = 0; e < 4; ++e) {
    int q = __float2int_rn(whh[r * 256 + k0 + e] * qm);
    q = min(127, max(-127, q));
    out |= ((uint32_t)(uint8_t)(int8_t)q) << (8 * e);
  }
  wq[i] = out;
}

// ---------------- GEMM: C[m,n] = sum_k A[m,k]*B[n,k] + bias[n] ----------------
// Staging via global_load_lds width=16 (R13-proven).
// R16: PERM=1 stores column n at position (n&255)*4 + (n>>8) — gate-interleaved
// xg layout so lstm reads one f16x4 per lane (exact same values, address-only).
// SWZ=1: bijective XCD swizzle (grid 8x256): XCD k gets a contiguous bm-slab,
// all bn -> B panel L2-resident per XCD (T1/m204 pattern).

template <int OUTF32, int PERM, int SWZ>
__global__ __launch_bounds__(256) void gemm_bt_kernel(
    const f16* __restrict__ A, const f16* __restrict__ B,
    const float* __restrict__ bias, void* __restrict__ Cout,
    int M, int N, int K) {
  __shared__ __align__(16) f16 Al[128 * 32];
  __shared__ __align__(16) f16 Bl[128 * 32];
  const int tid = threadIdx.x;
  const int lane = tid & 63, wave = tid >> 6;
  int bn, bm;
  if (SWZ) {
    int fid = blockIdx.y * gridDim.x + blockIdx.x;      // [0, 2048)
    int id2 = (fid & 7) * 256 + (fid >> 3);             // bijective remap
    bm = id2 >> 3;
    bn = id2 & 7;
  } else {
    bn = blockIdx.x;
    bm = blockIdx.y;
  }
  const int qm = (wave >> 1) * 64, qn = (wave & 1) * 64;

  f32x4 acc[4][4];
#pragma unroll
  for (int i = 0; i < 4; ++i)
#pragma unroll
    for (int j = 0; j < 4; ++j) acc[i][j] = (f32x4){0.f, 0.f, 0.f, 0.f};

  const int c0 = tid, c1 = 256 + tid;
  const int row0 = c0 >> 2, off0 = c0 & 3;
  const int row1 = c1 >> 2, off1 = c1 & 3;
  const int gmA0 = min(bm * 128 + row0, M - 1);
  const int gmA1 = min(bm * 128 + row1, M - 1);
  const int gnB0 = min(bn * 128 + row0, N - 1);
  const int gnB1 = min(bn * 128 + row1, N - 1);

  // wave-uniform LDS bases; HW writes base + lane*16
  f16* ldsA0 = &Al[(wave * 64) * 8];
  f16* ldsA1 = &Al[(256 + wave * 64) * 8];
  f16* ldsB0 = &Bl[(wave * 64) * 8];
  f16* ldsB1 = &Bl[(256 + wave * 64) * 8];

  for (int k0 = 0; k0 < K; k0 += 32) {
    __syncthreads();  // previous iteration's LDS frag reads done
    __builtin_amdgcn_global_load_lds(GLB_PTR(A + (size_t)gmA0 * K + k0 + off0 * 8),
                                     LDS_PTR(ldsA0), 16, 0, 0);
    __builtin_amdgcn_global_load_lds(GLB_PTR(A + (size_t)gmA1 * K + k0 + off1 * 8),
                                     LDS_PTR(ldsA1), 16, 0, 0);
    __builtin_amdgcn_global_load_lds(GLB_PTR(B + (size_t)gnB0 * K + k0 + off0 * 8),
                                     LDS_PTR(ldsB0), 16, 0, 0);
    __builtin_amdgcn_global_load_lds(GLB_PTR(B + (size_t)gnB1 * K + k0 + off1 * 8),
                                     LDS_PTR(ldsB1), 16, 0, 0);
    asm volatile("s_waitcnt vmcnt(0)" ::: "memory");
    __syncthreads();
    f16x8 af[4], bf[4];
#pragma unroll
    for (int mt = 0; mt < 4; ++mt)
      af[mt] = *(const f16x8*)&Al[(qm + mt * 16 + (lane & 15)) * 32 + (lane >> 4) * 8];
#pragma unroll
    for (int nt = 0; nt < 4; ++nt)
      bf[nt] = *(const f16x8*)&Bl[(qn + nt * 16 + (lane & 15)) * 32 + (lane >> 4) * 8];
#pragma unroll
    for (int mt = 0; mt < 4; ++mt)
#pragma unroll
      for (int nt = 0; nt < 4; ++nt)
        acc[mt][nt] = __builtin_amdgcn_mfma_f32_16x16x32_f16(af[mt], bf[nt], acc[mt][nt], 0, 0, 0);
  }

#pragma unroll
  for (int mt = 0; mt < 4; ++mt)
#pragma unroll
    for (int nt = 0; nt < 4; ++nt)
#pragma unroll
      for (int j = 0; j < 4; ++j) {
        int gm = bm * 128 + qm + mt * 16 + (lane >> 4) * 4 + j;
        int gn = bn * 128 + qn + nt * 16 + (lane & 15);
        if (gm < M && gn < N) {
          float v = acc[mt][nt][j] + bias[gn];
          if (OUTF32) {
            ((float*)Cout)[(size_t)gm * N + gn] = v;
          } else {
            int col = PERM ? ((gn & 255) * 4 + (gn >> 8)) : gn;
            ((f16*)Cout)[(size_t)gm * N + col] = (f16)v;
          }
        }
      }
}

// ---------------- persistent LSTM recurrence (int8 MFMA, two-level h) ----------------
// R15-proven geometry (432 us/layer, absmax 0.0078): 64 blocks x 512 threads (8 waves),
// 8 weight tiles/wave in AGPR, VGPR accs, zero-C first chunk, two-level h, kg-split
// activation (kg 0,1 -> uA cell; kg 2,3 -> uB cell; writes by kg 0 / kg 2).
// R16 delta: xg is gate-interleaved ([t][u*4+j]) -> ONE f16x4 load per lane per step
// replaces 4 scalar loads (values identical; address-only change).

__global__ __launch_bounds__(512, 2) void lstm_rec_kernel(
    const f16* __restrict__ xg,          // [B*T, 1024] gate-interleaved (u*4+j)
    const u32x4* __restrict__ wq,        // [64 t][4 c][64 l] u32x4 int8 frags
    const float* __restrict__ dmul,      // [1024] per-row dequant scale
    f16* __restrict__ h_out,             // [B*T, 256]
    int T) {
  __shared__ __align__(16) uint8_t h8[2][512];   // [hi 256 | lo 256], double-buffered
  const int b = blockIdx.x;
  const int tid = threadIdx.x;
  const int w = tid >> 6, lane = tid & 63;
  const int l15 = lane & 15, kg = (lane >> 4) & 3;
  const int base = w * 16 + l15;
  const int asel = ((l15 & 3) == 1) ? 256 : 0;  // rows 1,5,9,13 read lo slice
  const int sel = kg >> 1;                       // 0: this lane handles uA; 1: uB
  const int u = base + sel * 128;                // unit this lane processes

  // all 8 tiles -> AGPR (used only via "a" asm operands)
  u32x4 wt[8][4];
#pragma unroll
  for (int j = 0; j < 8; ++j)
#pragma unroll
    for (int c = 0; c < 4; ++c)
      wt[j][c] = wq[((w + 8 * j) * 4 + c) * 64 + lane];
  // scales for this lane's cell only: gate j of unit u -> dmul[u + 256*j]
  float sc[4], sc2[4];
#pragma unroll
  for (int j = 0; j < 4; ++j) {
    sc[j] = dmul[u + 256 * j];
    sc2[j] = sc[j] * (1.0f / 127.0f);
  }

  if (tid < 256) ((uint32_t*)h8)[tid] = 0;   // zero both buffers (1 KB)
  float cst = 0.f;
  __syncthreads();

  const f16* xt = xg + (size_t)b * T * 1024;
  f16* hob = h_out + (size_t)b * T * 256;

  // prologue: prefetch step-0 xg (one vector load: gates of unit u)
  f16x4 xc = *(const f16x4*)(xt + u * 4);

  const i32x4 zc = (i32x4){0, 0, 0, 0};

  for (int t = 0; t < T; ++t) {
    // consume prefetched xg; issue next step's load (hidden under this step)
    float xv0 = (float)xc[0], xv1 = (float)xc[1];
    float xv2 = (float)xc[2], xv3 = (float)xc[3];
    const f16* xn = (t + 1 < T) ? xt + 1024 : xt;
    xc = *(const f16x4*)(xn + u * 4);

    const uint8_t* hq = h8[t & 1] + asel;
    u32x4 afr0 = *(const u32x4*)(hq + 0 * 64 + kg * 16);
    i32x4 a0, a1, a2, a3, a4, a5, a6, a7;
    mfma_i8_z(a0, afr0, wt[0][0], zc);
    mfma_i8_z(a1, afr0, wt[1][0], zc);
    mfma_i8_z(a2, afr0, wt[2][0], zc);
    mfma_i8_z(a3, afr0, wt[3][0], zc);
    mfma_i8_z(a4, afr0, wt[4][0], zc);
    mfma_i8_z(a5, afr0, wt[5][0], zc);
    mfma_i8_z(a6, afr0, wt[6][0], zc);
    mfma_i8_z(a7, afr0, wt[7][0], zc);
#pragma unroll
    for (int c = 1; c < 4; ++c) {
      u32x4 afr = *(const u32x4*)(hq + c * 64 + kg * 16);
      mfma_i8(a0, afr, wt[0][c]);
      mfma_i8(a1, afr, wt[1][c]);
      mfma_i8(a2, afr, wt[2][c]);
      mfma_i8(a3, afr, wt[3][c]);
      mfma_i8(a4, afr, wt[4][c]);
      mfma_i8(a5, afr, wt[5][c]);
      mfma_i8(a6, afr, wt[6][c]);
      mfma_i8(a7, afr, wt[7][c]);
    }
    // this lane's cell: gate j -> acc tile 2j+sel; reg0 = hi, reg1 = lo (all kg valid)
    float dI0 = sel ? (float)a1[0] : (float)a0[0];
    float dI1 = sel ? (float)a1[1] : (float)a0[1];
    float dF0 = sel ? (float)a3[0] : (float)a2[0];
    float dF1 = sel ? (float)a3[1] : (float)a2[1];
    float dG0 = sel ? (float)a5[0] : (float)a4[0];
    float dG1 = sel ? (float)a5[1] : (float)a4[1];
    float dO0 = sel ? (float)a7[0] : (float)a6[0];
    float dO1 = sel ? (float)a7[1] : (float)a6[1];
    float gI = dI0 * sc[0] + dI1 * sc2[0] + xv0;
    float gF = dF0 * sc[1] + dF1 * sc2[1] + xv1;
    float gG = dG0 * sc[2] + dG1 * sc2[2] + xv2;
    float gO = dO0 * sc[3] + dO1 * sc2[3] + xv3;
    float iv = sigmoidf_(gI), fv = sigmoidf_(gF);
    float gv = tanhf_(gG),   ov = sigmoidf_(gO);
    cst = fv * cst + iv * gv;
    float hv = ov * tanhf_(cst);
    int hi = __float2int_rn(hv * 127.0f);
    int lo = __float2int_rn(fmaf((float)hi, -127.0f, hv * 16129.0f));
    uint8_t* hn = (uint8_t*)h8[(t + 1) & 1];
    if ((kg & 1) == 0) {   // kg==0 writes uA, kg==2 writes uB — each byte once
      hn[u] = (uint8_t)(int8_t)hi;
      hn[256 + u] = (uint8_t)(int8_t)lo;
      hob[(size_t)t * 256 + u] = (f16)hv;   // global h (vmcnt floats, never drained)
    }
    xt += 1024;
    asm volatile("s_waitcnt lgkmcnt(0)" ::: "memory");  // h8 writes visible
    __builtin_amdgcn_s_barrier();
    __builtin_amdgcn_sched_barrier(0);
  }
}

// ---------------- fused LayerNorm + attention pooling ----------------
// one block per batch, 256 threads.

__global__ __launch_bounds__(256) void ln_attn_kernel(
    const f16* __restrict__ h2, const float* __restrict__ lnw,
    const float* __restrict__ lnb, const float* __restrict__ aw,
    f16* __restrict__ att_out) {
  const int b = blockIdx.x, tid = threadIdx.x;
  const int lane = tid & 63, wave = tid >> 6;
  __shared__ float smu[512], sis[512], ssc[512];
  __shared__ float vbuf[256];
  __shared__ float red[16];

  float vj = aw[tid] * lnw[tid];
  float uj = aw[tid] * lnb[tid];
  vbuf[tid] = vj;
  float rv = vj, ru = uj;
#pragma unroll
  for (int m = 1; m < 64; m <<= 1) { rv += __shfl_xor(rv, m, 64); ru += __shfl_xor(ru, m, 64); }
  if (lane == 0) { red[wave] = rv; red[4 + wave] = ru; }
  __syncthreads();
  const float Vsum = red[0] + red[1] + red[2] + red[3];
  const float Csum = red[4] + red[5] + red[6] + red[7];
  const f32x4 v4 = *(const f32x4*)&vbuf[lane * 4];
  const f16* hb = h2 + (size_t)b * 512 * 256;

  for (int tt = wave; tt < 512; tt += 4) {
    f16x4 hv = *(const f16x4*)(hb + (size_t)tt * 256 + lane * 4);
    float h0 = (float)hv[0], h1 = (float)hv[1], h2v = (float)hv[2], h3 = (float)hv[3];
    float s1 = h0 + h1 + h2v + h3;
    float s2 = h0 * h0 + h1 * h1 + h2v * h2v + h3 * h3;
    float sv = h0 * v4[0] + h1 * v4[1] + h2v * v4[2] + h3 * v4[3];
#pragma unroll
    for (int m = 1; m < 64; m <<= 1) {
      s1 += __shfl_xor(s1, m, 64);
      s2 += __shfl_xor(s2, m, 64);
      sv += __shfl_xor(sv, m, 64);
    }
    if (lane == 0) {
      float mu = s1 * (1.0f / 256.0f);
      float var = s2 * (1.0f / 256.0f) - mu * mu;
      float is = rsqrtf(var + 1e-5f);
      smu[tt] = mu; sis[tt] = is;
      ssc[tt] = (sv - mu * Vsum) * is + Csum;
    }
  }
  __syncthreads();
  // softmax over 512 scores
  float a0 = ssc[tid], a1 = ssc[tid + 256];
  float mx = fmaxf(a0, a1);
#pragma unroll
  for (int m = 1; m < 64; m <<= 1) mx = fmaxf(mx, __shfl_xor(mx, m, 64));
  if (lane == 0) red[wave] = mx;
  __syncthreads();
  mx = fmaxf(fmaxf(red[0], red[1]), fmaxf(red[2], red[3]));
  __syncthreads();  // protect red reuse
  float p0 = exp2f((a0 - mx) * 1.44269504f);
  float p1 = exp2f((a1 - mx) * 1.44269504f);
  float ps = p0 + p1;
  float pm = p0 * smu[tid] * sis[tid] + p1 * smu[tid + 256] * sis[tid + 256];
#pragma unroll
  for (int m = 1; m < 64; m <<= 1) { ps += __shfl_xor(ps, m, 64); pm += __shfl_xor(pm, m, 64); }
  if (lane == 0) { red[wave] = ps; red[8 + wave] = pm; }
  __syncthreads();
  const float S = red[0] + red[1] + red[2] + red[3];
  const float PM = (red[8] + red[9] + red[10] + red[11]) / S;
  ssc[tid] = p0 / S * sis[tid];          // alpha_t
  ssc[tid + 256] = p1 / S * sis[tid + 256];
  __syncthreads();
  // pass 2: attended_j = lnw_j*(sum_t alpha_t h_tj - PM) + lnb_j
  float acc = 0.f;
  for (int t = 0; t < 512; ++t) acc += ssc[t] * (float)hb[(size_t)t * 256 + tid];
  float att = lnw[tid] * (acc - PM) + lnb[tid];
  att_out[b * 256 + tid] = (f16)att;
}

// ---------------- launch ----------------

extern "C" void kernel_launch(void* const* d_in, const int* in_sizes, int n_in,
                              void* d_out, int out_size, void* d_ws, size_t ws_size,
                              hipStream_t stream) {
  (void)in_sizes; (void)n_in; (void)out_size; (void)ws_size;
  const float* x    = (const float*)d_in[0];
  const float* wih0 = (const float*)d_in[1];
  const float* whh0 = (const float*)d_in[2];
  const float* bih0 = (const float*)d_in[3];
  const float* bhh0 = (const float*)d_in[4];
  const float* wih1 = (const float*)d_in[5];
  const float* whh1 = (const float*)d_in[6];
  const float* bih1 = (const float*)d_in[7];
  const float* bhh1 = (const float*)d_in[8];
  const float* lnw  = (const float*)d_in[9];
  const float* lnb  = (const float*)d_in[10];
  const float* aw   = (const float*)d_in[11];
  const float* fcw  = (const float*)d_in[12];
  const float* fcb  = (const float*)d_in[13];

  char* ws = (char*)d_ws;
  f16* x_h      = (f16*)(ws + 0);            // 50331648 B; region reused after GEMM0:
  f16* h1       = (f16*)(ws + 0);            //   h1: 16777216 B
  f16* h2       = (f16*)(ws + 16777216);     //   h2: 16777216 B
  f16* wih0_h   = (f16*)(ws + 50331648);     // 1572864
  f16* wih1_h   = (f16*)(ws + 51904512);     // 524288
  f16* fcw_h    = (f16*)(ws + 52428800);     // 15627264
  uint32_t* wq0 = (uint32_t*)(ws + 68056064);// 262144
  uint32_t* wq1 = (uint32_t*)(ws + 68318208);// 262144
  float* qmul0  = (float*)(ws + 68580352);   // 4096
  float* dmul0  = (float*)(ws + 68584448);   // 4096
  float* qmul1  = (float*)(ws + 68588544);   // 4096
  float* dmul1  = (float*)(ws + 68592640);   // 4096
  float* bsum0  = (float*)(ws + 69104640);   // 4096
  float* bsum1  = (float*)(ws + 69108736);   // 4096
  f16* att_h    = (f16*)(ws + 69112832);     // 32768
  f16* xg       = (f16*)(ws + 69145600);     // 67108864 (shared by both layers)

  convert_all_kernel<<<4096, 256, 0, stream>>>(x, x_h, wih0, wih0_h, wih1, wih1_h, fcw, fcw_h);
  addvec2_kernel<<<8, 256, 0, stream>>>(bih0, bhh0, bsum0, bih1, bhh1, bsum1);
  rowscale2_kernel<<<32, 256, 0, stream>>>(whh0, qmul0, dmul0, whh1, qmul1, dmul1);
  wq82_kernel<<<512, 256, 0, stream>>>(whh0, qmul0, wq0, whh1, qmul1, wq1);

  // layer 0: xg0 = x @ w_ih0^T + (b_ih0 + b_hh0), gate-interleaved output
  gemm_bt_kernel<0, 1, 1><<<dim3(8, 256), 256, 0, stream>>>(x_h, wih0_h, bsum0, xg, 32768, 1024, 768);
  lstm_rec_kernel<<<64, 512, 0, stream>>>(xg, (const u32x4*)wq0, dmul0, h1, 512);
  // layer 1
  gemm_bt_kernel<0, 1, 1><<<dim3(8, 256), 256, 0, stream>>>(h1, wih1_h, bsum1, xg, 32768, 1024, 256);
  lstm_rec_kernel<<<64, 512, 0, stream>>>(xg, (const u32x4*)wq1, dmul1, h2, 512);
  // LN + attention pooling
  ln_attn_kernel<<<64, 256, 0, stream>>>(h2, lnw, lnb, aw, att_h);
  // FC: out = attended @ fc_w^T + fc_b  (fp32 out, plain layout, no swizzle)
  gemm_bt_kernel<1, 0, 0><<<dim3(239, 1), 256, 0, stream>>>(att_h, fcw_h, fcb, d_out, 64, 30522, 256);
}